// Round 8
// baseline (290.086 us; speedup 1.0000x reference)
//
#include <hip/hip_runtime.h>
#include <stdint.h>

#define HID 256
#define NMAXPIX (1025 * 1025)
#define NREP 8     // histogram replicas, replica-major: hist[rep*NB + bin]
#define NSEG 2048  // selection segments (one wave each)
#define SELMAX 2112

// per-stage small-buffer layout (u32 units)
#define HISTA_OFF 0          // 8 x 2048
#define HISTB_OFF 16384      // 8 x 2048
#define HISTC_OFF 32768      // 8 x 1024
#define SCAL_OFF  40960      // [2]=pfx2 [3]=rem2 [6]=sel compaction counter
#define TIC_OFF   41024      // [0..511] lookback words, [512..1023] hist12 flags, [1024..1279] s1 event flags
#define STAGE_U32 43072

// stage-1 fused-kernel geometry
#define R1P 65
#define R1  129
#define N1  (129 * 129)
#define NPT1 4096u
#define SEG1 66        // 256*66 = 16896 >= 16641
#define B1 64          // blocks
#define NREP1 4
#define S1F(e) (1024 + 64 * (e))   // per-event flag base inside stage-0 tic

// ---------------- relaxed agent-scope atomic helpers (validated cheap path) ----------------
__device__ __forceinline__ uint32_t aload(const uint32_t* p) {
    return __hip_atomic_load(p, __ATOMIC_RELAXED, __HIP_MEMORY_SCOPE_AGENT);
}
__device__ __forceinline__ void astore(uint32_t* p, uint32_t v) {
    __hip_atomic_store(p, v, __ATOMIC_RELAXED, __HIP_MEMORY_SCOPE_AGENT);
}

// ---------------- MLP eval (single point), float4 LDS weight reads ----------------
__device__ __forceinline__ float mlp_eval4(float wx, float wy,
                                           const float4* __restrict__ w1x,
                                           const float4* __restrict__ w1y,
                                           const float4* __restrict__ vb1,
                                           const float4* __restrict__ vw2, float b2v) {
    const float C0 = (float)(0.5 / 1025.0);
    float px = (wx / 1025.0f + C0) * 2.0f - 1.0f;
    float py = (wy / 1025.0f + C0) * 2.0f - 1.0f;
    float a0 = 0.f, a1 = 0.f, a2 = 0.f, a3 = 0.f;
#pragma unroll 8
    for (int q = 0; q < HID / 4; ++q) {
        float4 a = w1x[q], b = w1y[q], c = vb1[q], d = vw2[q];
        float h0 = px * a.x + py * b.x + c.x;
        float h1 = px * a.y + py * b.y + c.y;
        float h2 = px * a.z + py * b.z + c.z;
        float h3 = px * a.w + py * b.w + c.w;
        h0 = h0 > 0.f ? h0 : 0.f;
        h1 = h1 > 0.f ? h1 : 0.f;
        h2 = h2 > 0.f ? h2 : 0.f;
        h3 = h3 > 0.f ? h3 : 0.f;
        a0 += h0 * d.x;
        a1 += h1 * d.y;
        a2 += h2 * d.z;
        a3 += h3 * d.w;
    }
    float x = ((a0 + a1) + (a2 + a3)) + b2v;
    float r;
    if (x >= 0.f) { r = 1.0f / (1.0f + expf(-x)); }
    else { float e = expf(x); r = e / (1.0f + e); }
    return r;
}

// ---------------- block exclusive scan helper (256 threads) ----------------
__device__ __forceinline__ uint32_t block_exscan_256(uint32_t v, volatile uint32_t* lds4) {
    int lane = threadIdx.x & 63, w = threadIdx.x >> 6;
    uint32_t inc = v;
#pragma unroll
    for (int d = 1; d < 64; d <<= 1) {
        uint32_t o = (uint32_t)__shfl_up((int)inc, d, 64);
        if (lane >= d) inc += o;
    }
    if (lane == 63) lds4[w] = inc;
    __syncthreads();
    uint32_t woff = 0;
    for (int i = 0; i < w; ++i) woff += lds4[i];
    return woff + inc - v;
}

// ---------------- redundant per-block radix scan (plain loads: prev-dispatch or LDS data) ----
__device__ void scan_generic(const uint32_t* __restrict__ hist, int NB, int nrep,
                             uint32_t rem_in, uint32_t prefix_in, int shift,
                             uint32_t* outp, uint32_t* outr,
                             volatile uint32_t* lds4, volatile uint32_t* ldspair) {
    int tid = threadIdx.x;
    int C = NB >> 8;                 // 8 (NB=2048) or 4 (NB=1024)
    int b0 = NB - (tid + 1) * C;     // thread 0 owns top bins
    uint32_t cnts[8];
#pragma unroll
    for (int k = 0; k < 8; ++k) cnts[k] = 0;
    for (int rep = 0; rep < nrep; ++rep) {
        const uint4* p = (const uint4*)(hist + (size_t)rep * NB + b0);
#pragma unroll
        for (int g = 0; g < 2; ++g) {
            if (g * 4 < C) {
                uint4 v = p[g];
                cnts[g * 4 + 0] += v.x;
                cnts[g * 4 + 1] += v.y;
                cnts[g * 4 + 2] += v.z;
                cnts[g * 4 + 3] += v.w;
            }
        }
    }
    uint32_t ssum = 0;
    for (int k = 0; k < C; ++k) ssum += cnts[k];
    uint32_t excl = block_exscan_256(ssum, lds4);
    uint32_t run = excl;
    for (int k = 0; k < C; ++k) {
        uint32_t c = cnts[C - 1 - k];   // descending bin order within thread
        if (rem_in > run && rem_in <= run + c) {
            ldspair[0] = (prefix_in << shift) | (uint32_t)(b0 + C - 1 - k);
            ldspair[1] = rem_in - run;
        }
        run += c;
    }
    __syncthreads();
    *outp = ldspair[0];
    *outr = ldspair[1];
}

// ---------------- same scan but via relaxed ATOMIC loads (same-kernel atomic-written data) ----
__device__ void scan_atomic(const uint32_t* __restrict__ hist, int NB, int nrep,
                            uint32_t rem_in, uint32_t prefix_in, int shift,
                            uint32_t* outp, uint32_t* outr,
                            volatile uint32_t* lds4, volatile uint32_t* ldspair) {
    int tid = threadIdx.x;
    int C = NB >> 8;
    int b0 = NB - (tid + 1) * C;
    uint32_t cnts[8];
#pragma unroll
    for (int k = 0; k < 8; ++k) cnts[k] = 0;
    for (int rep = 0; rep < nrep; ++rep)
        for (int k = 0; k < C; ++k)
            cnts[k] += aload(&hist[(size_t)rep * NB + b0 + k]);
    uint32_t ssum = 0;
    for (int k = 0; k < C; ++k) ssum += cnts[k];
    uint32_t excl = block_exscan_256(ssum, lds4);
    uint32_t run = excl;
    for (int k = 0; k < C; ++k) {
        uint32_t c = cnts[C - 1 - k];
        if (rem_in > run && rem_in <= run + c) {
            ldspair[0] = (prefix_in << shift) | (uint32_t)(b0 + C - 1 - k);
            ldspair[1] = rem_in - run;
        }
        run += c;
    }
    __syncthreads();
    *outp = ldspair[0];
    *outr = ldspair[1];
}

// ---------------- wave-aggregated LDS histogram add ----------------
__device__ __forceinline__ void hist_add(uint32_t* lh, uint32_t bin, bool act, int lane) {
    unsigned long long m = __ballot(act);
    if (m) {
        int leader = __ffsll(m) - 1;
        uint32_t lbin = (uint32_t)__shfl((int)bin, leader, 64);
        unsigned long long smk = __ballot(act && bin == lbin);
        if (smk == m) {
            if (lane == leader) atomicAdd(&lh[lbin], (uint32_t)__popcll(m));
        } else if (act) {
            atomicAdd(&lh[bin], 1u);
        }
    }
}

// ---------------- 2x bilinear upsample of one output pixel ----------------
__device__ __forceinline__ float up2x(const float* __restrict__ in, int rp, int r, int n) {
    int i = n / r, j = n % r;
    int i2 = i >> 1, j2 = j >> 1;
    float v;
    if ((i & 1) == 0) {
        if ((j & 1) == 0) {
            v = in[i2 * rp + j2];
        } else {
            float a = in[i2 * rp + j2], b = in[i2 * rp + j2 + 1];
            v = a * 0.5f + b * 0.5f;
        }
    } else {
        if ((j & 1) == 0) {
            float a = in[i2 * rp + j2], b = in[(i2 + 1) * rp + j2];
            v = a * 0.5f + b * 0.5f;
        } else {
            float a = in[i2 * rp + j2],      c = in[i2 * rp + j2 + 1];
            float b = in[(i2 + 1) * rp + j2], d = in[(i2 + 1) * rp + j2 + 1];
            float t1 = a * 0.5f + b * 0.5f;
            float t2 = c * 0.5f + d * 0.5f;
            v = t1 * 0.5f + t2 * 0.5f;
        }
    }
    return v;
}

__device__ __forceinline__ uint32_t mkkey(float v) {
    float unc = -fabsf(v - 0.5f);
    uint32_t u = __float_as_uint(unc);
    return (u & 0x80000000u) ? ~u : (u | 0x80000000u);
}

__device__ __forceinline__ uint32_t key_of(const float* __restrict__ in, int rp, int r, int n) {
    return mkkey(up2x(in, rp, r, n));
}

// ---------------- distributed-flag all-arrive sweep (bounded; never hangs) ----------------
// Each block published ONE distinct flag word; wave 0 polls all nflags distinct words
// (lookback-validated contention pattern: many lines, not one hot counter line).
__device__ bool sweep_flags(const uint32_t* flags, int nflags, volatile uint32_t* sflag,
                            int spincap) {
    int tid = threadIdx.x, lane = tid & 63;
    if (tid < 64) {
        uint32_t ok = 1;
        for (int base = 0; base < nflags; base += 64) {
            int idx = base + lane;
            if (idx < nflags) {
                uint32_t f = aload(&flags[idx]);
                int sp = 0;
                while (!f && sp < spincap) {
                    __builtin_amdgcn_s_sleep(2);
                    f = aload(&flags[idx]);
                    ++sp;
                }
                if (!f) ok = 0;
            }
        }
        unsigned long long bad = __ballot(ok == 0);
        if (lane == 0) *sflag = (bad == 0ull) ? 1u : 0u;
    }
    __syncthreads();
    return *sflag != 0;
}

// ---------------- eval0 + zero all per-stage buffers ----------------
__global__ __launch_bounds__(256) void k_eval0z(const float* __restrict__ w1, const float* __restrict__ b1,
                                                const float* __restrict__ w2, const float* __restrict__ b2,
                                                float* __restrict__ occ, uint32_t* __restrict__ zbuf, int zcount) {
    __shared__ alignas(16) float sw1[2 * HID];
    __shared__ alignas(16) float sb1[HID];
    __shared__ alignas(16) float sw2[HID];
    int tid = threadIdx.x;
    for (int i = tid; i < 2 * HID; i += 256) sw1[i] = w1[i];
    sb1[tid] = b1[tid];
    sw2[tid] = w2[tid];
    __syncthreads();
    int gtid = blockIdx.x * 256 + tid;
    int nthreads = gridDim.x * 256;
    for (int i = gtid; i < zcount; i += nthreads) zbuf[i] = 0;
    for (int n = gtid; n < 65 * 65; n += nthreads) {
        int i = n / 65, j = n % 65;
        occ[n] = mlp_eval4(16.0f * (float)j, 16.0f * (float)i,
                           (const float4*)sw1, (const float4*)(sw1 + HID),
                           (const float4*)sb1, (const float4*)sw2, b2[0]);
    }
}

// ================= stage 1 fully fused: 64 blocks, 4 distributed-flag events =================
// All cross-block within-kernel data (keys, hist bins, tie counts, flags) via relaxed
// agent-scope atomics. Every wait bounded with a fully-local recompute fallback from `in`.
__global__ __launch_bounds__(256) void k_s1all(const float* __restrict__ in,
                                               float* __restrict__ outg,
                                               uint32_t* __restrict__ keys,
                                               uint32_t* __restrict__ sm,
                                               const float* __restrict__ w1, const float* __restrict__ b1,
                                               const float* __restrict__ w2, const float* __restrict__ b2) {
    __shared__ alignas(16) float sw1[2 * HID];
    __shared__ alignas(16) float sb1[HID];
    __shared__ alignas(16) float sw2[HID];
    __shared__ alignas(16) uint32_t lh[2048];
    __shared__ uint32_t selidx[SELMAX];
    __shared__ uint32_t selcnt;
    __shared__ uint32_t lds4[4];
    __shared__ uint32_t ldspair[2];
    __shared__ uint32_t sflag;

    uint32_t* histA = sm + HISTA_OFF;
    uint32_t* histB = sm + HISTB_OFF;
    uint32_t* histC = sm + HISTC_OFF;
    uint32_t* tic   = sm + TIC_OFF;

    const int tid = threadIdx.x, lane = tid & 63, w = tid >> 6;
    for (int i = tid; i < 2 * HID; i += 256) sw1[i] = w1[i];
    sb1[tid] = b1[tid];
    sw2[tid] = w2[tid];
    if (tid == 0) selcnt = 0;
    for (int k = tid; k < 2048; k += 256) lh[k] = 0;
    __syncthreads();

    // ---- phase A: upsample + keys (atomic stores) + level-1 hist ----
    for (int n0 = blockIdx.x * 256; n0 < N1; n0 += B1 * 256) {
        int n = n0 + tid;
        bool act = n < N1;
        uint32_t key = 0;
        if (act) {
            float v = up2x(in, R1P, R1, n);
            outg[n] = v;                 // plain: consumed only by NEXT dispatch
            key = mkkey(v);
            astore(&keys[n], key);       // atomic: consumed within THIS kernel cross-block
        }
        hist_add(lh, key >> 21, act, lane);
    }
    __syncthreads();
    {
        uint32_t* rep = histA + (size_t)(blockIdx.x & (NREP1 - 1)) * 2048;
        for (int k = tid; k < 2048; k += 256) { uint32_t c = lh[k]; if (c) atomicAdd(&rep[k], c); }
    }
    __syncthreads();   // drains this block's vm ops before flag publish
    if (tid == 0) astore(&tic[S1F(0) + blockIdx.x], 1u);

    uint32_t pfx1, rem1;
    if (sweep_flags(&tic[S1F(0)], B1, &sflag, 4000)) {
        scan_atomic(histA, 2048, NREP1, NPT1, 0u, 0, &pfx1, &rem1, lds4, ldspair);
    } else {
        for (int k = tid; k < 2048; k += 256) lh[k] = 0;
        __syncthreads();
        for (int n0 = 0; n0 < N1; n0 += 256) {
            int n = n0 + tid; bool act = n < N1;
            uint32_t key = act ? key_of(in, R1P, R1, n) : 0u;
            hist_add(lh, key >> 21, act, lane);
        }
        __syncthreads();
        scan_generic(lh, 2048, 1, NPT1, 0u, 0, &pfx1, &rem1, lds4, ldspair);
    }

    // ---- phase B: level-2 hist ----
    for (int k = tid; k < 2048; k += 256) lh[k] = 0;
    __syncthreads();
    for (int n0 = blockIdx.x * 256; n0 < N1; n0 += B1 * 256) {
        int n = n0 + tid;
        bool act = n < N1;
        uint32_t key = act ? aload(&keys[n]) : 0u;
        bool flt = act && ((key >> 21) == pfx1);
        hist_add(lh, (key >> 10) & 0x7FFu, flt, lane);
    }
    __syncthreads();
    {
        uint32_t* rep = histB + (size_t)(blockIdx.x & (NREP1 - 1)) * 2048;
        for (int k = tid; k < 2048; k += 256) { uint32_t c = lh[k]; if (c) atomicAdd(&rep[k], c); }
    }
    __syncthreads();
    if (tid == 0) astore(&tic[S1F(1) + blockIdx.x], 1u);

    uint32_t pfx2, rem2;
    if (sweep_flags(&tic[S1F(1)], B1, &sflag, 4000)) {
        scan_atomic(histB, 2048, NREP1, rem1, pfx1, 11, &pfx2, &rem2, lds4, ldspair);
    } else {
        for (int k = tid; k < 2048; k += 256) lh[k] = 0;
        __syncthreads();
        for (int n0 = 0; n0 < N1; n0 += 256) {
            int n = n0 + tid; bool act = n < N1;
            uint32_t key = act ? key_of(in, R1P, R1, n) : 0u;
            bool flt = act && ((key >> 21) == pfx1);
            hist_add(lh, (key >> 10) & 0x7FFu, flt, lane);
        }
        __syncthreads();
        scan_generic(lh, 2048, 1, rem1, pfx1, 11, &pfx2, &rem2, lds4, ldspair);
    }

    // ---- phase C: level-3 hist (1024 bins) ----
    for (int k = tid; k < 2048; k += 256) lh[k] = 0;
    __syncthreads();
    for (int n0 = blockIdx.x * 256; n0 < N1; n0 += B1 * 256) {
        int n = n0 + tid;
        bool act = n < N1;
        uint32_t key = act ? aload(&keys[n]) : 0u;
        bool flt = act && ((key >> 10) == pfx2);
        hist_add(lh, key & 0x3FFu, flt, lane);
    }
    __syncthreads();
    {
        uint32_t* rep = histC + (size_t)(blockIdx.x & (NREP1 - 1)) * 1024;
        for (int k = tid; k < 1024; k += 256) { uint32_t c = lh[k]; if (c) atomicAdd(&rep[k], c); }
    }
    __syncthreads();
    if (tid == 0) astore(&tic[S1F(2) + blockIdx.x], 1u);

    uint32_t K, t;
    if (sweep_flags(&tic[S1F(2)], B1, &sflag, 4000)) {
        scan_atomic(histC, 1024, NREP1, rem2, pfx2, 10, &K, &t, lds4, ldspair);
    } else {
        for (int k = tid; k < 2048; k += 256) lh[k] = 0;
        __syncthreads();
        for (int n0 = 0; n0 < N1; n0 += 256) {
            int n = n0 + tid; bool act = n < N1;
            uint32_t key = act ? key_of(in, R1P, R1, n) : 0u;
            bool flt = act && ((key >> 10) == pfx2);
            hist_add(lh, key & 0x3FFu, flt, lane);
        }
        __syncthreads();
        scan_generic(lh, 1024, 1, rem2, pfx2, 10, &K, &t, lds4, ldspair);
    }

    // ---- phase D: per-wave tie counts, publish, distributed wait, prefix ----
    int wv = blockIdx.x * 4 + w;
    int s0 = wv * SEG1;
    int s1e = s0 + SEG1; if (s1e > N1) s1e = N1;
    uint32_t tcnt = 0;
    for (int base = s0; base < s1e; base += 64) {
        int n = base + lane;
        if (n < s1e) tcnt += (aload(&keys[n]) == K) ? 1u : 0u;
    }
#pragma unroll
    for (int d = 32; d; d >>= 1) tcnt += (uint32_t)__shfl_down((int)tcnt, d, 64);
    if (lane == 0) astore(&tic[wv], tcnt);
    __syncthreads();
    if (tid == 0) astore(&tic[S1F(3) + blockIdx.x], 1u);

    uint32_t tp = 0;
    if (sweep_flags(&tic[S1F(3)], B1, &sflag, 4000)) {
        for (int i = lane; i < wv; i += 64) tp += aload(&tic[i]);
    } else {
        for (int i = lane; i < wv; i += 64) {
            int a0 = i * SEG1, a1 = a0 + SEG1; if (a1 > N1) a1 = N1;
            uint32_t c = 0;
            for (int n2 = a0; n2 < a1; ++n2) c += (key_of(in, R1P, R1, n2) == K) ? 1u : 0u;
            tp += c;
        }
    }
#pragma unroll
    for (int d = 32; d; d >>= 1) tp += (uint32_t)__shfl_down((int)tp, d, 64);
    tp = (uint32_t)__shfl((int)tp, 0, 64);

    // ---- phase E: selection into LDS ----
    uint32_t tie_run = tp;
    unsigned long long lowmask = (lane == 63) ? ~0ull >> 1 : ((1ull << lane) - 1ull);
    for (int base = s0; base < s1e; base += 64) {
        int n = base + lane;
        bool inb = n < s1e;
        uint32_t key = inb ? aload(&keys[n]) : 0u;
        bool gt = inb && (key > K);
        bool tie = inb && (key == K);
        unsigned long long tm = __ballot(tie);
        uint32_t trank = tie_run + (uint32_t)__popcll(tm & lowmask);
        bool sel = gt || (tie && trank < t);
        unsigned long long smk = __ballot(sel);
        if (smk) {
            int leader = __ffsll(smk) - 1;
            uint32_t wbase = 0;
            if (lane == leader) wbase = atomicAdd(&selcnt, (uint32_t)__popcll(smk));
            wbase = (uint32_t)__shfl((int)wbase, leader, 64);
            if (sel) selidx[wbase + (uint32_t)__popcll(smk & lowmask)] = (uint32_t)n;
        }
        tie_run += (uint32_t)__popcll(tm);
    }
    __syncthreads();

    // ---- phase F: eval own selected points (<=264 per block at s1) ----
    uint32_t cnt = selcnt;
    float vb2 = b2[0];
    for (uint32_t i = tid; i < cnt; i += 256) {
        int n = (int)selidx[i];
        int ii = n / R1, jj = n % R1;
        float rr = mlp_eval4(8.0f * (float)jj, 8.0f * (float)ii,
                             (const float4*)sw1, (const float4*)(sw1 + HID),
                             (const float4*)sb1, (const float4*)sw2, vb2);
        outg[n] = rr;
    }
}

// ---------------- upsample 2x + key + msb-11 hist (grid-stride; LDS hist only) ----------------
__global__ __launch_bounds__(256) void k_upkey(const float* __restrict__ in, int rp,
                                               float* __restrict__ outg, int r, int nb, int bstride,
                                               uint32_t* __restrict__ keys,
                                               uint32_t* __restrict__ histA) {
    __shared__ uint32_t hist[2048];
    int tid = threadIdx.x;
    for (int k = tid; k < 2048; k += 256) hist[k] = 0;
    __syncthreads();
    int N = r * r;
    int lane = tid & 63;
    int gstride = gridDim.x * 256;
    for (int n0 = blockIdx.x * 256; n0 < N; n0 += gstride) {
        int n = n0 + tid;
        bool act = n < N;
        uint32_t key = 0;
        if (act) {
            float v = up2x(in, rp, r, n);
            for (int k = 0; k < nb; ++k) outg[(size_t)k * bstride + n] = v;
            key = mkkey(v);
            keys[n] = key;
        }
        hist_add(hist, key >> 21, act, lane);
    }
    __syncthreads();
    uint32_t* myrep = histA + (size_t)(blockIdx.x & (NREP - 1)) * 2048;
    for (int k = tid; k < 2048; k += 256) {
        uint32_t c = hist[k];
        if (c) atomicAdd(&myrep[k], c);
    }
}

// ---------------- fused level-2 + level-3 histogram (distributed-flag barrier inside) ----------
// Scans histA (prev dispatch, plain loads) -> builds histB replicas -> per-block flag ->
// sweep all flags -> scans histB via atomic loads -> builds histC replicas.
// Bounded sweep; on timeout, full local rebuild from keys (prev dispatch) -> G16-safe.
__global__ __launch_bounds__(256) void k_hist12(const uint32_t* __restrict__ keys, int N, uint32_t npt,
                                                const uint32_t* __restrict__ histA,
                                                uint32_t* __restrict__ scal,
                                                uint32_t* __restrict__ histB,
                                                uint32_t* __restrict__ histC,
                                                uint32_t* __restrict__ flags) {
    __shared__ uint32_t lh[2048];
    __shared__ uint32_t lds4[4];
    __shared__ uint32_t ldspair[2];
    __shared__ uint32_t sflag;
    int tid = threadIdx.x, lane = tid & 63;
    int gstride = gridDim.x * 256;

    // level-1 scan (histA complete since previous dispatch)
    uint32_t pfx1, rem1;
    scan_generic(histA, 2048, NREP, npt, 0u, 0, &pfx1, &rem1, lds4, ldspair);

    // build own-chunk level-2 hist
    for (int k = tid; k < 2048; k += 256) lh[k] = 0;
    __syncthreads();
    for (int base = blockIdx.x * 256; base < N; base += gstride) {
        int n = base + tid;
        bool inb = n < N;
        uint32_t key = inb ? keys[n] : 0u;
        bool flt = inb && ((key >> 21) == pfx1);
        hist_add(lh, (key >> 10) & 0x7FFu, flt, lane);
    }
    __syncthreads();
    {
        uint32_t* rep = histB + (size_t)(blockIdx.x & (NREP - 1)) * 2048;
        for (int k = tid; k < 2048; k += 256) { uint32_t c = lh[k]; if (c) atomicAdd(&rep[k], c); }
    }
    __syncthreads();   // drain adds before flag publish
    if (tid == 0) astore(&flags[blockIdx.x], 1u);

    // distributed all-arrive; then level-2 scan
    uint32_t pfx2, rem2;
    if (sweep_flags(flags, gridDim.x, &sflag, 4000)) {
        scan_atomic(histB, 2048, NREP, rem1, pfx1, 11, &pfx2, &rem2, lds4, ldspair);
    } else {
        // fallback: rebuild FULL level-2 hist locally from keys (bounded; no hang)
        for (int k = tid; k < 2048; k += 256) lh[k] = 0;
        __syncthreads();
        for (int n0 = 0; n0 < N; n0 += 256) {
            int n = n0 + tid; bool inb = n < N;
            uint32_t key = inb ? keys[n] : 0u;
            bool flt = inb && ((key >> 21) == pfx1);
            hist_add(lh, (key >> 10) & 0x7FFu, flt, lane);
        }
        __syncthreads();
        scan_generic(lh, 2048, 1, rem1, pfx1, 11, &pfx2, &rem2, lds4, ldspair);
    }
    if (blockIdx.x == 0 && tid == 0) { scal[2] = pfx2; scal[3] = rem2; }

    // build own-chunk level-3 hist (1024 bins); consumed by next dispatch (plain)
    for (int k = tid; k < 2048; k += 256) lh[k] = 0;
    __syncthreads();
    for (int base = blockIdx.x * 256; base < N; base += gstride) {
        int n = base + tid;
        bool inb = n < N;
        uint32_t key = inb ? keys[n] : 0u;
        bool flt = inb && ((key >> 10) == pfx2);
        hist_add(lh, key & 0x3FFu, flt, lane);
    }
    __syncthreads();
    {
        uint32_t* rep = histC + (size_t)(blockIdx.x & (NREP - 1)) * 1024;
        for (int k = tid; k < 1024; k += 256) { uint32_t c = lh[k]; if (c) atomicAdd(&rep[k], c); }
    }
}

// ---------------- fused final-scan + segcnt + selection + COMPACTION (no eval) ----------------
__global__ __launch_bounds__(256, 2) void k_segselc(
        const uint32_t* __restrict__ keys, int N, int seglen,
        const uint32_t* __restrict__ histC,
        const uint32_t* __restrict__ scal,
        uint32_t* __restrict__ tic,
        uint32_t* __restrict__ gcnt,
        uint32_t* __restrict__ selbuf) {
    __shared__ uint32_t selcnt;
    __shared__ uint32_t selidx[SELMAX];
    __shared__ uint32_t lds4[4];
    __shared__ uint32_t ldspair[2];
    __shared__ uint32_t wtc[4];
    __shared__ uint32_t s_excl;
    __shared__ uint32_t gbase;
    int tid = threadIdx.x, lane = tid & 63, w = tid >> 6;
    if (tid == 0) { selcnt = 0; s_excl = 0; }

    // K,t via redundant per-block scan of histC (built by previous dispatch)
    uint32_t rem2 = scal[3], pfx2 = scal[2];
    uint32_t K, t;
    scan_generic(histC, 1024, NREP, rem2, pfx2, 10, &K, &t, lds4, ldspair);

    // ---- per-wave tie count over own segment ----
    int wv = blockIdx.x * 4 + w;
    int s0 = wv * seglen;
    int s1 = s0 + seglen; if (s1 > N) s1 = N;
    uint32_t tcnt = 0;
    for (int base = s0; base < s1; base += 64) {
        int n = base + lane;
        if (n < s1) tcnt += (keys[n] == K) ? 1u : 0u;
    }
#pragma unroll
    for (int d = 32; d; d >>= 1) tcnt += (uint32_t)__shfl_down((int)tcnt, d, 64);
    if (lane == 0) wtc[w] = tcnt;
    __syncthreads();
    uint32_t agg = wtc[0] + wtc[1] + wtc[2] + wtc[3];
    uint32_t intra = 0;
    for (int i = 0; i < w; ++i) intra += wtc[i];

    // ---- publish aggregate; block 0 publishes inclusive directly ----
    if (tid == 0) {
        uint32_t st = (blockIdx.x == 0) ? ((2u << 30) | agg) : ((1u << 30) | agg);
        astore(&tic[blockIdx.x], st);
    }
    // ---- bounded decoupled lookback (wave 0, 64 predecessors per round) ----
    if (blockIdx.x > 0 && w == 0) {
        uint32_t excl = 0;
        int b = (int)blockIdx.x - 1;
        for (;;) {
            int mine = b - lane;
            bool active = (mine >= 0);
            uint32_t f = 0;
            if (active) {
                f = aload(&tic[mine]);
                int spins = 0;
                while ((f >> 30) == 0u && spins < 1000) {
                    __builtin_amdgcn_s_sleep(2);
                    f = aload(&tic[mine]);
                    ++spins;
                }
                if ((f >> 30) == 0u) {
                    int ms0 = mine * seglen;
                    int ms1 = ms0 + seglen; if (ms1 > N) ms1 = N;
                    uint32_t c = 0;
                    for (int n2 = ms0; n2 < ms1; ++n2) c += (keys[n2] == K) ? 1u : 0u;
                    f = (1u << 30) | c;
                }
            }
            unsigned long long incm = __ballot(active && (f >> 30) == 2u);
            uint32_t val;
            bool done = (incm != 0ull);
            if (done) {
                int l2 = __ffsll(incm) - 1;
                val = (lane <= l2) ? (f & 0x3FFFFFFFu) : 0u;
            } else {
                val = active ? (f & 0x3FFFFFFFu) : 0u;
            }
#pragma unroll
            for (int d = 32; d; d >>= 1) val += (uint32_t)__shfl_down((int)val, d, 64);
            val = (uint32_t)__shfl((int)val, 0, 64);
            excl += val;
            if (done) break;
            if (b < 64) break;
            b -= 64;
        }
        if (lane == 0) {
            astore(&tic[blockIdx.x], (2u << 30) | (excl + agg));
            s_excl = excl;
        }
    }
    __syncthreads();
    uint32_t tie_run = s_excl + intra;

    // ---- selection (keys L1-hot from the counting pass) ----
    unsigned long long lowmask = (lane == 63) ? ~0ull >> 1 : ((1ull << lane) - 1ull);
    for (int base = s0; base < s1; base += 64) {
        int n = base + lane;
        bool inb = n < s1;
        uint32_t key = inb ? keys[n] : 0u;
        bool gt = inb && (key > K);
        bool tie = inb && (key == K);
        unsigned long long tm = __ballot(tie);
        uint32_t trank = tie_run + (uint32_t)__popcll(tm & lowmask);
        bool sel = gt || (tie && trank < t);
        unsigned long long smk = __ballot(sel);
        if (smk) {
            int leader = __ffsll(smk) - 1;
            uint32_t wbase = 0;
            if (lane == leader) wbase = atomicAdd(&selcnt, (uint32_t)__popcll(smk));
            wbase = (uint32_t)__shfl((int)wbase, leader, 64);
            if (sel) selidx[wbase + (uint32_t)__popcll(smk & lowmask)] = (uint32_t)n;
        }
        tie_run += (uint32_t)__popcll(tm);
    }
    __syncthreads();

    // ---- compact to global selbuf (plain stores; consumed by NEXT dispatch) ----
    if (tid == 0) gbase = atomicAdd(gcnt, selcnt);
    __syncthreads();
    uint32_t cnt = selcnt, gb = gbase;
    for (uint32_t i = tid; i < cnt; i += 256) selbuf[gb + i] = selidx[i];
}

// ---------------- balanced eval of the compacted selection (exactly npt points) ----------------
__global__ __launch_bounds__(256) void k_evalsel(const uint32_t* __restrict__ selbuf, int npt,
                                                 int r, float stride,
                                                 float* __restrict__ occ, int nb, int bstride,
                                                 const float* __restrict__ w1, const float* __restrict__ b1,
                                                 const float* __restrict__ w2, const float* __restrict__ b2) {
    __shared__ alignas(16) float sw1[2 * HID];
    __shared__ alignas(16) float sb1[HID];
    __shared__ alignas(16) float sw2[HID];
    int tid = threadIdx.x;
    for (int i = tid; i < 2 * HID; i += 256) sw1[i] = w1[i];
    sb1[tid] = b1[tid];
    sw2[tid] = w2[tid];
    __syncthreads();
    float vb2 = b2[0];
    int gs = gridDim.x * 256;
    for (int i = blockIdx.x * 256 + tid; i < npt; i += gs) {
        int n = (int)selbuf[i];
        int ii = n / r, jj = n % r;
        float rr = mlp_eval4(stride * (float)jj, stride * (float)ii,
                             (const float4*)sw1, (const float4*)(sw1 + HID),
                             (const float4*)sb1, (const float4*)sw2, vb2);
        for (int k = 0; k < nb; ++k) occ[(size_t)k * bstride + n] = rr;
    }
}

// ---------------- fallback-only broadcast (used when d_ws is too small) ----------------
__global__ __launch_bounds__(256) void k_bcast(const float* __restrict__ src, float* __restrict__ dst, int N) {
    int q = blockIdx.x * 256 + threadIdx.x;
    int n = q * 4;
    if (n + 3 < N) {
        float4 v = *(const float4*)(src + n);
#pragma unroll
        for (int k = 0; k < 8; ++k) *(float4*)(dst + (size_t)k * N + n) = v;
    } else if (n < N) {
        for (int m = n; m < N; ++m) {
            float v = src[m];
#pragma unroll
            for (int k = 0; k < 8; ++k) dst[(size_t)k * N + m] = v;
        }
    }
}

extern "C" void kernel_launch(void* const* d_in, const int* in_sizes, int n_in,
                              void* d_out, int out_size, void* d_ws, size_t ws_size,
                              hipStream_t stream) {
    const float* w1 = (const float*)d_in[0];
    const float* b1 = (const float*)d_in[1];
    const float* w2 = (const float*)d_in[2];
    const float* b2 = (const float*)d_in[3];
    float* out = (float*)d_out;

    const size_t A = (((size_t)NMAXPIX * 4) + 255) & ~(size_t)255;  // one grid buffer
    const size_t SMALL_BYTES = (size_t)4 * STAGE_U32 * 4;            // 4 stage regions
    const size_t SELB_BYTES = ((size_t)262144 * 4 + 255) & ~(size_t)255;
    const size_t need = 3 * A + SMALL_BYTES + SELB_BYTES;

    int fused8 = (ws_size >= need);  // stage-4 writes all 8 batches directly only when ws holds scratch
    char* base = fused8 ? (char*)d_ws : (char*)d_out;
    float* buf0 = (float*)(base);
    float* buf1 = (float*)(base + A);
    uint32_t* keys = (uint32_t*)(base + 2 * A);
    uint32_t* smallb = (uint32_t*)(base + 3 * A);
    uint32_t* selbuf = (uint32_t*)(base + 3 * A + SMALL_BYTES);

    // dispatch 1: zero all stage buffers (hists, scal, tic incl. flags) + dense 65x65 eval
    k_eval0z<<<dim3(512), dim3(256), 0, stream>>>(w1, b1, w2, b2, buf0, smallb, 4 * STAGE_U32);

    // ---- stage 1 (129x129): ONE fused kernel, 64 blocks, distributed-flag events ----
    k_s1all<<<dim3(B1), dim3(256), 0, stream>>>(buf0, buf1, keys, smallb, w1, b1, w2, b2);

    const int resA[5] = {65, 129, 257, 513, 1025};
    const int nptA[5] = {0, 4096, 16384, 65536, 262144};
    float* cur = buf1;
    float* nxt = buf0;
    for (int s = 2; s < 5; ++s) {
        int rp = resA[s - 1], r = resA[s];
        int N = r * r;
        uint32_t npt = (uint32_t)nptA[s];
        uint32_t* sm    = smallb + (size_t)(s - 1) * STAGE_U32;
        uint32_t* histA = sm + HISTA_OFF;
        uint32_t* histB = sm + HISTB_OFF;
        uint32_t* histC = sm + HISTC_OFF;
        uint32_t* scal  = sm + SCAL_OFF;
        uint32_t* tic   = sm + TIC_OFF;
        int nb1 = (N + 255) / 256;
        int nbu = nb1 < 1024 ? nb1 : 1024;
        int seglen = (N + NSEG - 1) / NSEG;
        float stride = 1024.0f / (float)(r - 1);

        int last = (s == 4);
        float* stage_out = (last && fused8) ? out : nxt;
        int nb = (last && fused8) ? 8 : 1;
        int bstride = (last && fused8) ? NMAXPIX : 0;

        int nbe = (int)((npt + 255) / 256); if (nbe > 512) nbe = 512;

        k_upkey<<<dim3(nbu), dim3(256), 0, stream>>>(cur, rp, stage_out, r, nb, bstride, keys, histA);
        k_hist12<<<dim3(512), dim3(256), 0, stream>>>(keys, N, npt, histA, scal,
                                                      histB, histC, tic + 512);
        k_segselc<<<dim3(NSEG / 4), dim3(256), 0, stream>>>(keys, N, seglen, histC, scal, tic,
                                                            scal + 6, selbuf);
        k_evalsel<<<dim3(nbe), dim3(256), 0, stream>>>(selbuf, (int)npt, r, stride,
                                                       stage_out, nb, bstride, w1, b1, w2, b2);
        if (!(last && fused8)) { float* tmp = cur; cur = nxt; nxt = tmp; }
    }
    if (!fused8) {
        // fallback: scratch lived in d_out; final grid is at cur
        k_bcast<<<dim3(((NMAXPIX + 3) / 4 + 255) / 256), dim3(256), 0, stream>>>(cur, out, NMAXPIX);
    }
}

// Round 9
// 256.312 us; speedup vs baseline: 1.1318x; 1.1318x over previous
//
#include <hip/hip_runtime.h>
#include <stdint.h>

#define HID 256
#define NMAXPIX (1025 * 1025)
#define NREP 8     // histogram replicas, replica-major: hist[rep*NB + bin]
#define NSEG2 4096 // selection segments for stages 2-4 (one wave each; 1024 blocks)
#define SELMAX 2112

// per-stage small-buffer layout (u32 units)
#define HISTA_OFF 0          // 8 x 2048
#define HISTB_OFF 16384      // 8 x 2048
#define HISTC_OFF 32768      // 8 x 1024
#define SCAL_OFF  40960      // [0..5] radix state, [6]=sel compaction counter, [8..11]=s1 event counters
#define TIC_OFF   41024      // 2048 tie-count / lookback words
#define STAGE_U32 43072

// stage-1 fused-kernel geometry
#define R1P 65
#define R1  129
#define N1  (129 * 129)
#define NPT1 4096u
#define SEG1 66        // 256*66 = 16896 >= 16641
#define B1 64          // blocks
#define NREP1 4

// ---------------- relaxed agent-scope atomic helpers (validated cheap path) ----------------
__device__ __forceinline__ uint32_t aload(const uint32_t* p) {
    return __hip_atomic_load(p, __ATOMIC_RELAXED, __HIP_MEMORY_SCOPE_AGENT);
}
__device__ __forceinline__ void astore(uint32_t* p, uint32_t v) {
    __hip_atomic_store(p, v, __ATOMIC_RELAXED, __HIP_MEMORY_SCOPE_AGENT);
}

// ---------------- MLP eval (single point), float4 LDS weight reads ----------------
__device__ __forceinline__ float mlp_eval4(float wx, float wy,
                                           const float4* __restrict__ w1x,
                                           const float4* __restrict__ w1y,
                                           const float4* __restrict__ vb1,
                                           const float4* __restrict__ vw2, float b2v) {
    const float C0 = (float)(0.5 / 1025.0);
    float px = (wx / 1025.0f + C0) * 2.0f - 1.0f;
    float py = (wy / 1025.0f + C0) * 2.0f - 1.0f;
    float a0 = 0.f, a1 = 0.f, a2 = 0.f, a3 = 0.f;
#pragma unroll 8
    for (int q = 0; q < HID / 4; ++q) {
        float4 a = w1x[q], b = w1y[q], c = vb1[q], d = vw2[q];
        float h0 = px * a.x + py * b.x + c.x;
        float h1 = px * a.y + py * b.y + c.y;
        float h2 = px * a.z + py * b.z + c.z;
        float h3 = px * a.w + py * b.w + c.w;
        h0 = h0 > 0.f ? h0 : 0.f;
        h1 = h1 > 0.f ? h1 : 0.f;
        h2 = h2 > 0.f ? h2 : 0.f;
        h3 = h3 > 0.f ? h3 : 0.f;
        a0 += h0 * d.x;
        a1 += h1 * d.y;
        a2 += h2 * d.z;
        a3 += h3 * d.w;
    }
    float x = ((a0 + a1) + (a2 + a3)) + b2v;
    float r;
    if (x >= 0.f) { r = 1.0f / (1.0f + expf(-x)); }
    else { float e = expf(x); r = e / (1.0f + e); }
    return r;
}

// ---------------- block exclusive scan helper (256 threads) ----------------
__device__ __forceinline__ uint32_t block_exscan_256(uint32_t v, volatile uint32_t* lds4) {
    int lane = threadIdx.x & 63, w = threadIdx.x >> 6;
    uint32_t inc = v;
#pragma unroll
    for (int d = 1; d < 64; d <<= 1) {
        uint32_t o = (uint32_t)__shfl_up((int)inc, d, 64);
        if (lane >= d) inc += o;
    }
    if (lane == 63) lds4[w] = inc;
    __syncthreads();
    uint32_t woff = 0;
    for (int i = 0; i < w; ++i) woff += lds4[i];
    return woff + inc - v;
}

// ---------------- redundant per-block radix scan (plain loads: prev-dispatch or LDS data) ----
__device__ void scan_generic(const uint32_t* __restrict__ hist, int NB, int nrep,
                             uint32_t rem_in, uint32_t prefix_in, int shift,
                             uint32_t* outp, uint32_t* outr,
                             volatile uint32_t* lds4, volatile uint32_t* ldspair) {
    int tid = threadIdx.x;
    int C = NB >> 8;                 // 8 (NB=2048) or 4 (NB=1024)
    int b0 = NB - (tid + 1) * C;     // thread 0 owns top bins
    uint32_t cnts[8];
#pragma unroll
    for (int k = 0; k < 8; ++k) cnts[k] = 0;
    for (int rep = 0; rep < nrep; ++rep) {
        const uint4* p = (const uint4*)(hist + (size_t)rep * NB + b0);
#pragma unroll
        for (int g = 0; g < 2; ++g) {
            if (g * 4 < C) {
                uint4 v = p[g];
                cnts[g * 4 + 0] += v.x;
                cnts[g * 4 + 1] += v.y;
                cnts[g * 4 + 2] += v.z;
                cnts[g * 4 + 3] += v.w;
            }
        }
    }
    uint32_t ssum = 0;
    for (int k = 0; k < C; ++k) ssum += cnts[k];
    uint32_t excl = block_exscan_256(ssum, lds4);
    uint32_t run = excl;
    for (int k = 0; k < C; ++k) {
        uint32_t c = cnts[C - 1 - k];   // descending bin order within thread
        if (rem_in > run && rem_in <= run + c) {
            ldspair[0] = (prefix_in << shift) | (uint32_t)(b0 + C - 1 - k);
            ldspair[1] = rem_in - run;
        }
        run += c;
    }
    __syncthreads();
    *outp = ldspair[0];
    *outr = ldspair[1];
}

// ---------------- same scan but via relaxed ATOMIC loads (same-kernel atomic-written data) ----
__device__ void scan_atomic(const uint32_t* __restrict__ hist, int NB, int nrep,
                            uint32_t rem_in, uint32_t prefix_in, int shift,
                            uint32_t* outp, uint32_t* outr,
                            volatile uint32_t* lds4, volatile uint32_t* ldspair) {
    int tid = threadIdx.x;
    int C = NB >> 8;
    int b0 = NB - (tid + 1) * C;
    uint32_t cnts[8];
#pragma unroll
    for (int k = 0; k < 8; ++k) cnts[k] = 0;
    for (int rep = 0; rep < nrep; ++rep)
        for (int k = 0; k < C; ++k)
            cnts[k] += aload(&hist[(size_t)rep * NB + b0 + k]);
    uint32_t ssum = 0;
    for (int k = 0; k < C; ++k) ssum += cnts[k];
    uint32_t excl = block_exscan_256(ssum, lds4);
    uint32_t run = excl;
    for (int k = 0; k < C; ++k) {
        uint32_t c = cnts[C - 1 - k];
        if (rem_in > run && rem_in <= run + c) {
            ldspair[0] = (prefix_in << shift) | (uint32_t)(b0 + C - 1 - k);
            ldspair[1] = rem_in - run;
        }
        run += c;
    }
    __syncthreads();
    *outp = ldspair[0];
    *outr = ldspair[1];
}

// ---------------- wave-aggregated LDS histogram add ----------------
__device__ __forceinline__ void hist_add(uint32_t* lh, uint32_t bin, bool act, int lane) {
    unsigned long long m = __ballot(act);
    if (m) {
        int leader = __ffsll(m) - 1;
        uint32_t lbin = (uint32_t)__shfl((int)bin, leader, 64);
        unsigned long long smk = __ballot(act && bin == lbin);
        if (smk == m) {
            if (lane == leader) atomicAdd(&lh[lbin], (uint32_t)__popcll(m));
        } else if (act) {
            atomicAdd(&lh[bin], 1u);
        }
    }
}

// ---------------- 2x bilinear upsample of one output pixel ----------------
__device__ __forceinline__ float up2x(const float* __restrict__ in, int rp, int r, int n) {
    int i = n / r, j = n % r;
    int i2 = i >> 1, j2 = j >> 1;
    float v;
    if ((i & 1) == 0) {
        if ((j & 1) == 0) {
            v = in[i2 * rp + j2];
        } else {
            float a = in[i2 * rp + j2], b = in[i2 * rp + j2 + 1];
            v = a * 0.5f + b * 0.5f;
        }
    } else {
        if ((j & 1) == 0) {
            float a = in[i2 * rp + j2], b = in[(i2 + 1) * rp + j2];
            v = a * 0.5f + b * 0.5f;
        } else {
            float a = in[i2 * rp + j2],      c = in[i2 * rp + j2 + 1];
            float b = in[(i2 + 1) * rp + j2], d = in[(i2 + 1) * rp + j2 + 1];
            float t1 = a * 0.5f + b * 0.5f;
            float t2 = c * 0.5f + d * 0.5f;
            v = t1 * 0.5f + t2 * 0.5f;
        }
    }
    return v;
}

__device__ __forceinline__ uint32_t mkkey(float v) {
    float unc = -fabsf(v - 0.5f);
    uint32_t u = __float_as_uint(unc);
    return (u & 0x80000000u) ? ~u : (u | 0x80000000u);
}

__device__ __forceinline__ uint32_t key_of(const float* __restrict__ in, int rp, int r, int n) {
    return mkkey(up2x(in, rp, r, n));
}

// ---------------- bounded all-arrived wait on a counter (64-block scale only) ----------------
__device__ bool wait_ctr(uint32_t* ctr, uint32_t target, volatile uint32_t* sflag) {
    if (threadIdx.x == 0) {
        uint32_t d = aload(ctr);
        int sp = 0;
        while (d < target && sp < 20000) {
            __builtin_amdgcn_s_sleep(4);
            d = aload(ctr);
            ++sp;
        }
        *sflag = (d >= target) ? 1u : 0u;
    }
    __syncthreads();
    return *sflag != 0;
}

// ---------------- eval0 + zero all per-stage buffers ----------------
__global__ __launch_bounds__(256) void k_eval0z(const float* __restrict__ w1, const float* __restrict__ b1,
                                                const float* __restrict__ w2, const float* __restrict__ b2,
                                                float* __restrict__ occ, uint32_t* __restrict__ zbuf, int zcount) {
    __shared__ alignas(16) float sw1[2 * HID];
    __shared__ alignas(16) float sb1[HID];
    __shared__ alignas(16) float sw2[HID];
    int tid = threadIdx.x;
    for (int i = tid; i < 2 * HID; i += 256) sw1[i] = w1[i];
    sb1[tid] = b1[tid];
    sw2[tid] = w2[tid];
    __syncthreads();
    int gtid = blockIdx.x * 256 + tid;
    int nthreads = gridDim.x * 256;
    for (int i = gtid; i < zcount; i += nthreads) zbuf[i] = 0;
    for (int n = gtid; n < 65 * 65; n += nthreads) {
        int i = n / 65, j = n % 65;
        occ[n] = mlp_eval4(16.0f * (float)j, 16.0f * (float)i,
                           (const float4*)sw1, (const float4*)(sw1 + HID),
                           (const float4*)sb1, (const float4*)sw2, b2[0]);
    }
}

// ================= stage 1 fully fused: 64 blocks, 4 counter events (round-7 validated) ======
__global__ __launch_bounds__(256) void k_s1all(const float* __restrict__ in,
                                               float* __restrict__ outg,
                                               uint32_t* __restrict__ keys,
                                               uint32_t* __restrict__ sm,
                                               const float* __restrict__ w1, const float* __restrict__ b1,
                                               const float* __restrict__ w2, const float* __restrict__ b2) {
    __shared__ alignas(16) float sw1[2 * HID];
    __shared__ alignas(16) float sb1[HID];
    __shared__ alignas(16) float sw2[HID];
    __shared__ alignas(16) uint32_t lh[2048];
    __shared__ uint32_t selidx[SELMAX];
    __shared__ uint32_t selcnt;
    __shared__ uint32_t lds4[4];
    __shared__ uint32_t ldspair[2];
    __shared__ uint32_t sflag;

    uint32_t* histA = sm + HISTA_OFF;
    uint32_t* histB = sm + HISTB_OFF;
    uint32_t* histC = sm + HISTC_OFF;
    uint32_t* scal  = sm + SCAL_OFF;
    uint32_t* tic   = sm + TIC_OFF;

    const int tid = threadIdx.x, lane = tid & 63, w = tid >> 6;
    for (int i = tid; i < 2 * HID; i += 256) sw1[i] = w1[i];
    sb1[tid] = b1[tid];
    sw2[tid] = w2[tid];
    if (tid == 0) selcnt = 0;
    for (int k = tid; k < 2048; k += 256) lh[k] = 0;
    __syncthreads();

    // ---- phase A: upsample + keys (atomic stores) + level-1 hist ----
    for (int n0 = blockIdx.x * 256; n0 < N1; n0 += B1 * 256) {
        int n = n0 + tid;
        bool act = n < N1;
        uint32_t key = 0;
        if (act) {
            float v = up2x(in, R1P, R1, n);
            outg[n] = v;                 // plain: consumed only by NEXT dispatch
            key = mkkey(v);
            astore(&keys[n], key);       // atomic: consumed within THIS kernel cross-block
        }
        hist_add(lh, key >> 21, act, lane);
    }
    __syncthreads();
    {
        uint32_t* rep = histA + (size_t)(blockIdx.x & (NREP1 - 1)) * 2048;
        for (int k = tid; k < 2048; k += 256) { uint32_t c = lh[k]; if (c) atomicAdd(&rep[k], c); }
    }
    __syncthreads();   // drains this block's vm ops before arrival publish
    if (tid == 0) __hip_atomic_fetch_add(&scal[8], 1u, __ATOMIC_RELAXED, __HIP_MEMORY_SCOPE_AGENT);

    uint32_t pfx1, rem1;
    if (wait_ctr(&scal[8], B1, &sflag)) {
        scan_atomic(histA, 2048, NREP1, NPT1, 0u, 0, &pfx1, &rem1, lds4, ldspair);
    } else {
        for (int k = tid; k < 2048; k += 256) lh[k] = 0;
        __syncthreads();
        for (int n0 = 0; n0 < N1; n0 += 256) {
            int n = n0 + tid; bool act = n < N1;
            uint32_t key = act ? key_of(in, R1P, R1, n) : 0u;
            hist_add(lh, key >> 21, act, lane);
        }
        __syncthreads();
        scan_generic(lh, 2048, 1, NPT1, 0u, 0, &pfx1, &rem1, lds4, ldspair);
    }

    // ---- phase B: level-2 hist ----
    for (int k = tid; k < 2048; k += 256) lh[k] = 0;
    __syncthreads();
    for (int n0 = blockIdx.x * 256; n0 < N1; n0 += B1 * 256) {
        int n = n0 + tid;
        bool act = n < N1;
        uint32_t key = act ? aload(&keys[n]) : 0u;
        bool flt = act && ((key >> 21) == pfx1);
        hist_add(lh, (key >> 10) & 0x7FFu, flt, lane);
    }
    __syncthreads();
    {
        uint32_t* rep = histB + (size_t)(blockIdx.x & (NREP1 - 1)) * 2048;
        for (int k = tid; k < 2048; k += 256) { uint32_t c = lh[k]; if (c) atomicAdd(&rep[k], c); }
    }
    __syncthreads();
    if (tid == 0) __hip_atomic_fetch_add(&scal[9], 1u, __ATOMIC_RELAXED, __HIP_MEMORY_SCOPE_AGENT);

    uint32_t pfx2, rem2;
    if (wait_ctr(&scal[9], B1, &sflag)) {
        scan_atomic(histB, 2048, NREP1, rem1, pfx1, 11, &pfx2, &rem2, lds4, ldspair);
    } else {
        for (int k = tid; k < 2048; k += 256) lh[k] = 0;
        __syncthreads();
        for (int n0 = 0; n0 < N1; n0 += 256) {
            int n = n0 + tid; bool act = n < N1;
            uint32_t key = act ? key_of(in, R1P, R1, n) : 0u;
            bool flt = act && ((key >> 21) == pfx1);
            hist_add(lh, (key >> 10) & 0x7FFu, flt, lane);
        }
        __syncthreads();
        scan_generic(lh, 2048, 1, rem1, pfx1, 11, &pfx2, &rem2, lds4, ldspair);
    }

    // ---- phase C: level-3 hist (1024 bins) ----
    for (int k = tid; k < 2048; k += 256) lh[k] = 0;
    __syncthreads();
    for (int n0 = blockIdx.x * 256; n0 < N1; n0 += B1 * 256) {
        int n = n0 + tid;
        bool act = n < N1;
        uint32_t key = act ? aload(&keys[n]) : 0u;
        bool flt = act && ((key >> 10) == pfx2);
        hist_add(lh, key & 0x3FFu, flt, lane);
    }
    __syncthreads();
    {
        uint32_t* rep = histC + (size_t)(blockIdx.x & (NREP1 - 1)) * 1024;
        for (int k = tid; k < 1024; k += 256) { uint32_t c = lh[k]; if (c) atomicAdd(&rep[k], c); }
    }
    __syncthreads();
    if (tid == 0) __hip_atomic_fetch_add(&scal[10], 1u, __ATOMIC_RELAXED, __HIP_MEMORY_SCOPE_AGENT);

    uint32_t K, t;
    if (wait_ctr(&scal[10], B1, &sflag)) {
        scan_atomic(histC, 1024, NREP1, rem2, pfx2, 10, &K, &t, lds4, ldspair);
    } else {
        for (int k = tid; k < 2048; k += 256) lh[k] = 0;
        __syncthreads();
        for (int n0 = 0; n0 < N1; n0 += 256) {
            int n = n0 + tid; bool act = n < N1;
            uint32_t key = act ? key_of(in, R1P, R1, n) : 0u;
            bool flt = act && ((key >> 10) == pfx2);
            hist_add(lh, key & 0x3FFu, flt, lane);
        }
        __syncthreads();
        scan_generic(lh, 1024, 1, rem2, pfx2, 10, &K, &t, lds4, ldspair);
    }

    // ---- phase D: per-wave tie counts, publish, wait, prefix ----
    int wv = blockIdx.x * 4 + w;
    int s0 = wv * SEG1;
    int s1e = s0 + SEG1; if (s1e > N1) s1e = N1;
    uint32_t tcnt = 0;
    for (int base = s0; base < s1e; base += 64) {
        int n = base + lane;
        if (n < s1e) tcnt += (aload(&keys[n]) == K) ? 1u : 0u;
    }
#pragma unroll
    for (int d = 32; d; d >>= 1) tcnt += (uint32_t)__shfl_down((int)tcnt, d, 64);
    if (lane == 0) astore(&tic[wv], tcnt);
    __syncthreads();
    if (tid == 0) __hip_atomic_fetch_add(&scal[11], 1u, __ATOMIC_RELAXED, __HIP_MEMORY_SCOPE_AGENT);

    uint32_t tp = 0;
    if (wait_ctr(&scal[11], B1, &sflag)) {
        for (int i = lane; i < wv; i += 64) tp += aload(&tic[i]);
    } else {
        for (int i = lane; i < wv; i += 64) {
            int a0 = i * SEG1, a1 = a0 + SEG1; if (a1 > N1) a1 = N1;
            uint32_t c = 0;
            for (int n2 = a0; n2 < a1; ++n2) c += (key_of(in, R1P, R1, n2) == K) ? 1u : 0u;
            tp += c;
        }
    }
#pragma unroll
    for (int d = 32; d; d >>= 1) tp += (uint32_t)__shfl_down((int)tp, d, 64);
    tp = (uint32_t)__shfl((int)tp, 0, 64);

    // ---- phase E: selection into LDS ----
    uint32_t tie_run = tp;
    unsigned long long lowmask = (lane == 63) ? ~0ull >> 1 : ((1ull << lane) - 1ull);
    for (int base = s0; base < s1e; base += 64) {
        int n = base + lane;
        bool inb = n < s1e;
        uint32_t key = inb ? aload(&keys[n]) : 0u;
        bool gt = inb && (key > K);
        bool tie = inb && (key == K);
        unsigned long long tm = __ballot(tie);
        uint32_t trank = tie_run + (uint32_t)__popcll(tm & lowmask);
        bool sel = gt || (tie && trank < t);
        unsigned long long smk = __ballot(sel);
        if (smk) {
            int leader = __ffsll(smk) - 1;
            uint32_t wbase = 0;
            if (lane == leader) wbase = atomicAdd(&selcnt, (uint32_t)__popcll(smk));
            wbase = (uint32_t)__shfl((int)wbase, leader, 64);
            if (sel) selidx[wbase + (uint32_t)__popcll(smk & lowmask)] = (uint32_t)n;
        }
        tie_run += (uint32_t)__popcll(tm);
    }
    __syncthreads();

    // ---- phase F: eval own selected points (<=264 per block at s1) ----
    uint32_t cnt = selcnt;
    float vb2 = b2[0];
    for (uint32_t i = tid; i < cnt; i += 256) {
        int n = (int)selidx[i];
        int ii = n / R1, jj = n % R1;
        float rr = mlp_eval4(8.0f * (float)jj, 8.0f * (float)ii,
                             (const float4*)sw1, (const float4*)(sw1 + HID),
                             (const float4*)sb1, (const float4*)sw2, vb2);
        outg[n] = rr;
    }
}

// ---------------- upsample 2x + key + msb-11 hist (grid-stride; LDS hist only) ----------------
__global__ __launch_bounds__(256) void k_upkey(const float* __restrict__ in, int rp,
                                               float* __restrict__ outg, int r, int nb, int bstride,
                                               uint32_t* __restrict__ keys,
                                               uint32_t* __restrict__ histA) {
    __shared__ uint32_t hist[2048];
    int tid = threadIdx.x;
    for (int k = tid; k < 2048; k += 256) hist[k] = 0;
    __syncthreads();
    int N = r * r;
    int lane = tid & 63;
    int gstride = gridDim.x * 256;
    for (int n0 = blockIdx.x * 256; n0 < N; n0 += gstride) {
        int n = n0 + tid;
        bool act = n < N;
        uint32_t key = 0;
        if (act) {
            float v = up2x(in, rp, r, n);
            for (int k = 0; k < nb; ++k) outg[(size_t)k * bstride + n] = v;
            key = mkkey(v);
            keys[n] = key;
        }
        hist_add(hist, key >> 21, act, lane);
    }
    __syncthreads();
    uint32_t* myrep = histA + (size_t)(blockIdx.x & (NREP - 1)) * 2048;
    for (int k = tid; k < 2048; k += 256) {
        uint32_t c = hist[k];
        if (c) atomicAdd(&myrep[k], c);
    }
}

// ---------------- filtered histogram pass (uint4 key loads; scan of prev hist fused in) -------
__global__ __launch_bounds__(256) void k_histmid(const uint32_t* __restrict__ keys, int N,
                                                 const uint32_t* __restrict__ prevHist,
                                                 uint32_t* __restrict__ scal,
                                                 int useNpt, uint32_t npt, int scalInIdx, int shift,
                                                 int scalOutIdx,
                                                 int fshift, int bshift, uint32_t bmask,
                                                 uint32_t* __restrict__ outHist, int NBout) {
    __shared__ uint32_t lh[2048];
    __shared__ uint32_t lds4[4];
    __shared__ uint32_t ldspair[2];
    int tid = threadIdx.x, lane = tid & 63;
    uint32_t rem_in = useNpt ? npt : scal[scalInIdx + 1];
    uint32_t pfx_in = useNpt ? 0u  : scal[scalInIdx];
    uint32_t pfx, rem;
    scan_generic(prevHist, 2048, NREP, rem_in, pfx_in, shift, &pfx, &rem, lds4, ldspair);
    if (blockIdx.x == 0 && tid == 0) { scal[scalOutIdx] = pfx; scal[scalOutIdx + 1] = rem; }
    for (int k = tid; k < 2048; k += 256) lh[k] = 0;
    __syncthreads();
    // 4 keys per thread (order-free for histograms); keys is 16B-aligned, n multiple of 4
    int gstride4 = gridDim.x * 1024;
    for (int base = blockIdx.x * 1024; base < N; base += gstride4) {
        int n = base + tid * 4;
        uint32_t k0 = 0, k1 = 0, k2 = 0, k3 = 0;
        if (n + 3 < N) {
            uint4 v = *(const uint4*)(keys + n);
            k0 = v.x; k1 = v.y; k2 = v.z; k3 = v.w;
        } else {
            if (n < N) k0 = keys[n];
            if (n + 1 < N) k1 = keys[n + 1];
            if (n + 2 < N) k2 = keys[n + 2];
            if (n + 3 < N) k3 = keys[n + 3];
        }
        hist_add(lh, (k0 >> bshift) & bmask, (n < N) && ((k0 >> fshift) == pfx), lane);
        hist_add(lh, (k1 >> bshift) & bmask, (n + 1 < N) && ((k1 >> fshift) == pfx), lane);
        hist_add(lh, (k2 >> bshift) & bmask, (n + 2 < N) && ((k2 >> fshift) == pfx), lane);
        hist_add(lh, (k3 >> bshift) & bmask, (n + 3 < N) && ((k3 >> fshift) == pfx), lane);
    }
    __syncthreads();
    uint32_t* myrep = outHist + (size_t)(blockIdx.x & (NREP - 1)) * NBout;
    for (int k = tid; k < NBout; k += 256) {
        uint32_t c = lh[k];
        if (c) atomicAdd(&myrep[k], c);
    }
}

// ---------------- fused final-scan + segcnt + selection + COMPACTION (no eval) ----------------
// 1024 blocks (NSEG2=4096 wave-segments): halves per-wave serial key loops vs NSEG=2048.
// Cross-block traffic: per-block flag word in tic[] via relaxed agent-scope atomics; spin
// bounded; fallback reads keys (complete since k_upkey's dispatch) -> no hang, G16-safe.
__global__ __launch_bounds__(256, 4) void k_segselc(
        const uint32_t* __restrict__ keys, int N, int seglen,
        const uint32_t* __restrict__ histC,
        const uint32_t* __restrict__ scal,
        uint32_t* __restrict__ tic,
        uint32_t* __restrict__ gcnt,
        uint32_t* __restrict__ selbuf) {
    __shared__ uint32_t selcnt;
    __shared__ uint32_t selidx[SELMAX];
    __shared__ uint32_t lds4[4];
    __shared__ uint32_t ldspair[2];
    __shared__ uint32_t wtc[4];
    __shared__ uint32_t s_excl;
    __shared__ uint32_t gbase;
    int tid = threadIdx.x, lane = tid & 63, w = tid >> 6;
    if (tid == 0) { selcnt = 0; s_excl = 0; }

    // K,t via redundant per-block scan of histC (built by previous dispatch)
    uint32_t rem2 = scal[3], pfx2 = scal[2];
    uint32_t K, t;
    scan_generic(histC, 1024, NREP, rem2, pfx2, 10, &K, &t, lds4, ldspair);

    // ---- per-wave tie count over own segment ----
    int wv = blockIdx.x * 4 + w;
    int s0 = wv * seglen;
    int s1 = s0 + seglen; if (s1 > N) s1 = N;
    uint32_t tcnt = 0;
    for (int base = s0; base < s1; base += 64) {
        int n = base + lane;
        if (n < s1) tcnt += (keys[n] == K) ? 1u : 0u;
    }
#pragma unroll
    for (int d = 32; d; d >>= 1) tcnt += (uint32_t)__shfl_down((int)tcnt, d, 64);
    if (lane == 0) wtc[w] = tcnt;
    __syncthreads();
    uint32_t agg = wtc[0] + wtc[1] + wtc[2] + wtc[3];
    uint32_t intra = 0;
    for (int i = 0; i < w; ++i) intra += wtc[i];

    // ---- publish aggregate; block 0 publishes inclusive directly ----
    if (tid == 0) {
        uint32_t st = (blockIdx.x == 0) ? ((2u << 30) | agg) : ((1u << 30) | agg);
        astore(&tic[blockIdx.x], st);
    }
    // ---- bounded decoupled lookback (wave 0, 64 predecessors per round) ----
    if (blockIdx.x > 0 && w == 0) {
        uint32_t excl = 0;
        int b = (int)blockIdx.x - 1;
        for (;;) {
            int mine = b - lane;
            bool active = (mine >= 0);
            uint32_t f = 0;
            if (active) {
                f = aload(&tic[mine]);
                int spins = 0;
                while ((f >> 30) == 0u && spins < 1000) {
                    __builtin_amdgcn_s_sleep(2);
                    f = aload(&tic[mine]);
                    ++spins;
                }
                if ((f >> 30) == 0u) {
                    int ms0 = mine * seglen;
                    int ms1 = ms0 + seglen; if (ms1 > N) ms1 = N;
                    uint32_t c = 0;
                    for (int n2 = ms0; n2 < ms1; ++n2) c += (keys[n2] == K) ? 1u : 0u;
                    f = (1u << 30) | c;
                }
            }
            unsigned long long incm = __ballot(active && (f >> 30) == 2u);
            uint32_t val;
            bool done = (incm != 0ull);
            if (done) {
                int l2 = __ffsll(incm) - 1;
                val = (lane <= l2) ? (f & 0x3FFFFFFFu) : 0u;
            } else {
                val = active ? (f & 0x3FFFFFFFu) : 0u;
            }
#pragma unroll
            for (int d = 32; d; d >>= 1) val += (uint32_t)__shfl_down((int)val, d, 64);
            val = (uint32_t)__shfl((int)val, 0, 64);
            excl += val;
            if (done) break;
            if (b < 64) break;
            b -= 64;
        }
        if (lane == 0) {
            astore(&tic[blockIdx.x], (2u << 30) | (excl + agg));
            s_excl = excl;
        }
    }
    __syncthreads();
    uint32_t tie_run = s_excl + intra;

    // ---- selection (keys L1-hot from the counting pass) ----
    unsigned long long lowmask = (lane == 63) ? ~0ull >> 1 : ((1ull << lane) - 1ull);
    for (int base = s0; base < s1; base += 64) {
        int n = base + lane;
        bool inb = n < s1;
        uint32_t key = inb ? keys[n] : 0u;
        bool gt = inb && (key > K);
        bool tie = inb && (key == K);
        unsigned long long tm = __ballot(tie);
        uint32_t trank = tie_run + (uint32_t)__popcll(tm & lowmask);
        bool sel = gt || (tie && trank < t);
        unsigned long long smk = __ballot(sel);
        if (smk) {
            int leader = __ffsll(smk) - 1;
            uint32_t wbase = 0;
            if (lane == leader) wbase = atomicAdd(&selcnt, (uint32_t)__popcll(smk));
            wbase = (uint32_t)__shfl((int)wbase, leader, 64);
            if (sel) selidx[wbase + (uint32_t)__popcll(smk & lowmask)] = (uint32_t)n;
        }
        tie_run += (uint32_t)__popcll(tm);
    }
    __syncthreads();

    // ---- compact to global selbuf (plain stores; consumed by NEXT dispatch) ----
    if (tid == 0) gbase = atomicAdd(gcnt, selcnt);
    __syncthreads();
    uint32_t cnt = selcnt, gb = gbase;
    for (uint32_t i = tid; i < cnt; i += 256) selbuf[gb + i] = selidx[i];
}

// ---------------- balanced eval of the compacted selection (2 points/thread, shared reads) ----
__global__ __launch_bounds__(256) void k_evalsel(const uint32_t* __restrict__ selbuf, int npt,
                                                 int r, float stride,
                                                 float* __restrict__ occ, int nb, int bstride,
                                                 const float* __restrict__ w1, const float* __restrict__ b1,
                                                 const float* __restrict__ w2, const float* __restrict__ b2) {
    __shared__ alignas(16) float sw1[2 * HID];
    __shared__ alignas(16) float sb1[HID];
    __shared__ alignas(16) float sw2[HID];
    int tid = threadIdx.x;
    for (int i = tid; i < 2 * HID; i += 256) sw1[i] = w1[i];
    sb1[tid] = b1[tid];
    sw2[tid] = w2[tid];
    __syncthreads();
    float vb2 = b2[0];
    const float4* w1x = (const float4*)sw1;
    const float4* w1y = (const float4*)(sw1 + HID);
    const float4* vb1 = (const float4*)sb1;
    const float4* vw2 = (const float4*)sw2;
    const float C0 = (float)(0.5 / 1025.0);
    int gs2 = gridDim.x * 512;
    for (int bb = blockIdx.x * 512; bb < npt; bb += gs2) {
        int i0 = bb + tid, i1 = bb + tid + 256;
        bool v0 = i0 < npt, v1 = i1 < npt;
        int nA = v0 ? (int)selbuf[i0] : 0;
        int nB = v1 ? (int)selbuf[i1] : 0;
        int iA = nA / r, jA = nA % r;
        int iB = nB / r, jB = nB % r;
        float pxA = ((stride * (float)jA) / 1025.0f + C0) * 2.0f - 1.0f;
        float pyA = ((stride * (float)iA) / 1025.0f + C0) * 2.0f - 1.0f;
        float pxB = ((stride * (float)jB) / 1025.0f + C0) * 2.0f - 1.0f;
        float pyB = ((stride * (float)iB) / 1025.0f + C0) * 2.0f - 1.0f;
        float4 A0 = {0, 0, 0, 0}, A1 = {0, 0, 0, 0};
#pragma unroll 4
        for (int q = 0; q < HID / 4; ++q) {
            float4 a = w1x[q], b = w1y[q], c = vb1[q], d = vw2[q];
            {
                float h0 = pxA * a.x + pyA * b.x + c.x;
                float h1 = pxA * a.y + pyA * b.y + c.y;
                float h2 = pxA * a.z + pyA * b.z + c.z;
                float h3 = pxA * a.w + pyA * b.w + c.w;
                h0 = h0 > 0.f ? h0 : 0.f;
                h1 = h1 > 0.f ? h1 : 0.f;
                h2 = h2 > 0.f ? h2 : 0.f;
                h3 = h3 > 0.f ? h3 : 0.f;
                A0.x += h0 * d.x; A0.y += h1 * d.y;
                A0.z += h2 * d.z; A0.w += h3 * d.w;
            }
            {
                float h0 = pxB * a.x + pyB * b.x + c.x;
                float h1 = pxB * a.y + pyB * b.y + c.y;
                float h2 = pxB * a.z + pyB * b.z + c.z;
                float h3 = pxB * a.w + pyB * b.w + c.w;
                h0 = h0 > 0.f ? h0 : 0.f;
                h1 = h1 > 0.f ? h1 : 0.f;
                h2 = h2 > 0.f ? h2 : 0.f;
                h3 = h3 > 0.f ? h3 : 0.f;
                A1.x += h0 * d.x; A1.y += h1 * d.y;
                A1.z += h2 * d.z; A1.w += h3 * d.w;
            }
        }
        if (v0) {
            float x = ((A0.x + A0.y) + (A0.z + A0.w)) + vb2;
            float rr;
            if (x >= 0.f) { rr = 1.0f / (1.0f + expf(-x)); }
            else { float e = expf(x); rr = e / (1.0f + e); }
            for (int k = 0; k < nb; ++k) occ[(size_t)k * bstride + nA] = rr;
        }
        if (v1) {
            float x = ((A1.x + A1.y) + (A1.z + A1.w)) + vb2;
            float rr;
            if (x >= 0.f) { rr = 1.0f / (1.0f + expf(-x)); }
            else { float e = expf(x); rr = e / (1.0f + e); }
            for (int k = 0; k < nb; ++k) occ[(size_t)k * bstride + nB] = rr;
        }
    }
}

// ---------------- fallback-only broadcast (used when d_ws is too small) ----------------
__global__ __launch_bounds__(256) void k_bcast(const float* __restrict__ src, float* __restrict__ dst, int N) {
    int q = blockIdx.x * 256 + threadIdx.x;
    int n = q * 4;
    if (n + 3 < N) {
        float4 v = *(const float4*)(src + n);
#pragma unroll
        for (int k = 0; k < 8; ++k) *(float4*)(dst + (size_t)k * N + n) = v;
    } else if (n < N) {
        for (int m = n; m < N; ++m) {
            float v = src[m];
#pragma unroll
            for (int k = 0; k < 8; ++k) dst[(size_t)k * N + m] = v;
        }
    }
}

extern "C" void kernel_launch(void* const* d_in, const int* in_sizes, int n_in,
                              void* d_out, int out_size, void* d_ws, size_t ws_size,
                              hipStream_t stream) {
    const float* w1 = (const float*)d_in[0];
    const float* b1 = (const float*)d_in[1];
    const float* w2 = (const float*)d_in[2];
    const float* b2 = (const float*)d_in[3];
    float* out = (float*)d_out;

    const size_t A = (((size_t)NMAXPIX * 4) + 255) & ~(size_t)255;  // one grid buffer
    const size_t SMALL_BYTES = (size_t)4 * STAGE_U32 * 4;            // 4 stage regions
    const size_t SELB_BYTES = ((size_t)262144 * 4 + 255) & ~(size_t)255;
    const size_t need = 3 * A + SMALL_BYTES + SELB_BYTES;

    int fused8 = (ws_size >= need);  // stage-4 writes all 8 batches directly only when ws holds scratch
    char* base = fused8 ? (char*)d_ws : (char*)d_out;
    float* buf0 = (float*)(base);
    float* buf1 = (float*)(base + A);
    uint32_t* keys = (uint32_t*)(base + 2 * A);
    uint32_t* smallb = (uint32_t*)(base + 3 * A);
    uint32_t* selbuf = (uint32_t*)(base + 3 * A + SMALL_BYTES);

    // dispatch 1: zero all stage buffers (hists, scal incl. counters, tic) + dense 65x65 eval
    k_eval0z<<<dim3(512), dim3(256), 0, stream>>>(w1, b1, w2, b2, buf0, smallb, 4 * STAGE_U32);

    // ---- stage 1 (129x129): ONE fused kernel, 64 blocks, counter events ----
    k_s1all<<<dim3(B1), dim3(256), 0, stream>>>(buf0, buf1, keys, smallb, w1, b1, w2, b2);

    const int resA[5] = {65, 129, 257, 513, 1025};
    const int nptA[5] = {0, 4096, 16384, 65536, 262144};
    float* cur = buf1;
    float* nxt = buf0;
    for (int s = 2; s < 5; ++s) {
        int rp = resA[s - 1], r = resA[s];
        int N = r * r;
        uint32_t npt = (uint32_t)nptA[s];
        uint32_t* sm    = smallb + (size_t)(s - 1) * STAGE_U32;
        uint32_t* histA = sm + HISTA_OFF;
        uint32_t* histB = sm + HISTB_OFF;
        uint32_t* histC = sm + HISTC_OFF;
        uint32_t* scal  = sm + SCAL_OFF;
        uint32_t* tic   = sm + TIC_OFF;
        int nb1 = (N + 255) / 256;
        int nbu = nb1 < 1024 ? nb1 : 1024;
        int seglen = (N + NSEG2 - 1) / NSEG2;
        float stride = 1024.0f / (float)(r - 1);

        int last = (s == 4);
        float* stage_out = (last && fused8) ? out : nxt;
        int nb = (last && fused8) ? 8 : 1;
        int bstride = (last && fused8) ? NMAXPIX : 0;

        int nbe = (int)((npt + 511) / 512); if (nbe > 512) nbe = 512;

        k_upkey<<<dim3(nbu), dim3(256), 0, stream>>>(cur, rp, stage_out, r, nb, bstride, keys, histA);
        k_histmid<<<dim3(512), dim3(256), 0, stream>>>(keys, N, histA, scal, 1, npt, 0, 0,
                                                       0, 21, 10, 0x7FFu, histB, 2048);
        k_histmid<<<dim3(512), dim3(256), 0, stream>>>(keys, N, histB, scal, 0, 0u, 0, 11,
                                                       2, 10, 0, 0x3FFu, histC, 1024);
        k_segselc<<<dim3(NSEG2 / 4), dim3(256), 0, stream>>>(keys, N, seglen, histC, scal, tic,
                                                             scal + 6, selbuf);
        k_evalsel<<<dim3(nbe), dim3(256), 0, stream>>>(selbuf, (int)npt, r, stride,
                                                       stage_out, nb, bstride, w1, b1, w2, b2);
        if (!(last && fused8)) { float* tmp = cur; cur = nxt; nxt = tmp; }
    }
    if (!fused8) {
        // fallback: scratch lived in d_out; final grid is at cur
        k_bcast<<<dim3(((NMAXPIX + 3) / 4 + 255) / 256), dim3(256), 0, stream>>>(cur, out, NMAXPIX);
    }
}

// Round 10
// 229.611 us; speedup vs baseline: 1.2634x; 1.1163x over previous
//
#include <hip/hip_runtime.h>
#include <stdint.h>

#define HID 256
#define NMAXPIX (1025 * 1025)
#define NREP 8     // histogram replicas, replica-major: hist[rep*NB + bin]
#define NSEG 2048  // selection segments (one wave each; 512 blocks)
#define SELMAX 2112

// per-stage small-buffer layout (u32 units)
#define HISTA_OFF 0          // 8 x 2048
#define HISTB_OFF 16384      // 8 x 2048
#define HISTC_OFF 32768      // 8 x 1024
#define SCAL_OFF  40960      // [0..5] radix state, [8..11]=s1 event counters
#define TIC_OFF   41024      // 2048 u32: s1 tie counts; stages 2-4: 512 u64 pair-lookback flags
#define STAGE_U32 43072

// stage-1 fused-kernel geometry
#define R1P 65
#define R1  129
#define N1  (129 * 129)
#define NPT1 4096u
#define SEG1 66        // 256*66 = 16896 >= 16641
#define B1 64          // blocks
#define NREP1 4

// ---------------- relaxed agent-scope atomic helpers (validated cheap path) ----------------
__device__ __forceinline__ uint32_t aload(const uint32_t* p) {
    return __hip_atomic_load(p, __ATOMIC_RELAXED, __HIP_MEMORY_SCOPE_AGENT);
}
__device__ __forceinline__ void astore(uint32_t* p, uint32_t v) {
    __hip_atomic_store(p, v, __ATOMIC_RELAXED, __HIP_MEMORY_SCOPE_AGENT);
}
__device__ __forceinline__ unsigned long long aload64(const unsigned long long* p) {
    return __hip_atomic_load(p, __ATOMIC_RELAXED, __HIP_MEMORY_SCOPE_AGENT);
}
__device__ __forceinline__ void astore64(unsigned long long* p, unsigned long long v) {
    __hip_atomic_store(p, v, __ATOMIC_RELAXED, __HIP_MEMORY_SCOPE_AGENT);
}

// ---------------- MLP eval (single point), float4 LDS weight reads ----------------
__device__ __forceinline__ float mlp_eval4(float wx, float wy,
                                           const float4* __restrict__ w1x,
                                           const float4* __restrict__ w1y,
                                           const float4* __restrict__ vb1,
                                           const float4* __restrict__ vw2, float b2v) {
    const float C0 = (float)(0.5 / 1025.0);
    float px = (wx / 1025.0f + C0) * 2.0f - 1.0f;
    float py = (wy / 1025.0f + C0) * 2.0f - 1.0f;
    float a0 = 0.f, a1 = 0.f, a2 = 0.f, a3 = 0.f;
#pragma unroll 8
    for (int q = 0; q < HID / 4; ++q) {
        float4 a = w1x[q], b = w1y[q], c = vb1[q], d = vw2[q];
        float h0 = px * a.x + py * b.x + c.x;
        float h1 = px * a.y + py * b.y + c.y;
        float h2 = px * a.z + py * b.z + c.z;
        float h3 = px * a.w + py * b.w + c.w;
        h0 = h0 > 0.f ? h0 : 0.f;
        h1 = h1 > 0.f ? h1 : 0.f;
        h2 = h2 > 0.f ? h2 : 0.f;
        h3 = h3 > 0.f ? h3 : 0.f;
        a0 += h0 * d.x;
        a1 += h1 * d.y;
        a2 += h2 * d.z;
        a3 += h3 * d.w;
    }
    float x = ((a0 + a1) + (a2 + a3)) + b2v;
    float r;
    if (x >= 0.f) { r = 1.0f / (1.0f + expf(-x)); }
    else { float e = expf(x); r = e / (1.0f + e); }
    return r;
}

// ---------------- block exclusive scan helper (256 threads) ----------------
__device__ __forceinline__ uint32_t block_exscan_256(uint32_t v, volatile uint32_t* lds4) {
    int lane = threadIdx.x & 63, w = threadIdx.x >> 6;
    uint32_t inc = v;
#pragma unroll
    for (int d = 1; d < 64; d <<= 1) {
        uint32_t o = (uint32_t)__shfl_up((int)inc, d, 64);
        if (lane >= d) inc += o;
    }
    if (lane == 63) lds4[w] = inc;
    __syncthreads();
    uint32_t woff = 0;
    for (int i = 0; i < w; ++i) woff += lds4[i];
    return woff + inc - v;
}

// ---------------- redundant per-block radix scan (plain loads: prev-dispatch or LDS data) ----
__device__ void scan_generic(const uint32_t* __restrict__ hist, int NB, int nrep,
                             uint32_t rem_in, uint32_t prefix_in, int shift,
                             uint32_t* outp, uint32_t* outr,
                             volatile uint32_t* lds4, volatile uint32_t* ldspair) {
    int tid = threadIdx.x;
    int C = NB >> 8;                 // 8 (NB=2048) or 4 (NB=1024)
    int b0 = NB - (tid + 1) * C;     // thread 0 owns top bins
    uint32_t cnts[8];
#pragma unroll
    for (int k = 0; k < 8; ++k) cnts[k] = 0;
    for (int rep = 0; rep < nrep; ++rep) {
        const uint4* p = (const uint4*)(hist + (size_t)rep * NB + b0);
#pragma unroll
        for (int g = 0; g < 2; ++g) {
            if (g * 4 < C) {
                uint4 v = p[g];
                cnts[g * 4 + 0] += v.x;
                cnts[g * 4 + 1] += v.y;
                cnts[g * 4 + 2] += v.z;
                cnts[g * 4 + 3] += v.w;
            }
        }
    }
    uint32_t ssum = 0;
    for (int k = 0; k < C; ++k) ssum += cnts[k];
    uint32_t excl = block_exscan_256(ssum, lds4);
    uint32_t run = excl;
    for (int k = 0; k < C; ++k) {
        uint32_t c = cnts[C - 1 - k];   // descending bin order within thread
        if (rem_in > run && rem_in <= run + c) {
            ldspair[0] = (prefix_in << shift) | (uint32_t)(b0 + C - 1 - k);
            ldspair[1] = rem_in - run;
        }
        run += c;
    }
    __syncthreads();
    *outp = ldspair[0];
    *outr = ldspair[1];
}

// ---------------- same scan but via relaxed ATOMIC loads (same-kernel atomic-written data) ----
__device__ void scan_atomic(const uint32_t* __restrict__ hist, int NB, int nrep,
                            uint32_t rem_in, uint32_t prefix_in, int shift,
                            uint32_t* outp, uint32_t* outr,
                            volatile uint32_t* lds4, volatile uint32_t* ldspair) {
    int tid = threadIdx.x;
    int C = NB >> 8;
    int b0 = NB - (tid + 1) * C;
    uint32_t cnts[8];
#pragma unroll
    for (int k = 0; k < 8; ++k) cnts[k] = 0;
    for (int rep = 0; rep < nrep; ++rep)
        for (int k = 0; k < C; ++k)
            cnts[k] += aload(&hist[(size_t)rep * NB + b0 + k]);
    uint32_t ssum = 0;
    for (int k = 0; k < C; ++k) ssum += cnts[k];
    uint32_t excl = block_exscan_256(ssum, lds4);
    uint32_t run = excl;
    for (int k = 0; k < C; ++k) {
        uint32_t c = cnts[C - 1 - k];
        if (rem_in > run && rem_in <= run + c) {
            ldspair[0] = (prefix_in << shift) | (uint32_t)(b0 + C - 1 - k);
            ldspair[1] = rem_in - run;
        }
        run += c;
    }
    __syncthreads();
    *outp = ldspair[0];
    *outr = ldspair[1];
}

// ---------------- wave-aggregated LDS histogram add ----------------
__device__ __forceinline__ void hist_add(uint32_t* lh, uint32_t bin, bool act, int lane) {
    unsigned long long m = __ballot(act);
    if (m) {
        int leader = __ffsll(m) - 1;
        uint32_t lbin = (uint32_t)__shfl((int)bin, leader, 64);
        unsigned long long smk = __ballot(act && bin == lbin);
        if (smk == m) {
            if (lane == leader) atomicAdd(&lh[lbin], (uint32_t)__popcll(m));
        } else if (act) {
            atomicAdd(&lh[bin], 1u);
        }
    }
}

// ---------------- 2x bilinear upsample of one output pixel ----------------
__device__ __forceinline__ float up2x(const float* __restrict__ in, int rp, int r, int n) {
    int i = n / r, j = n % r;
    int i2 = i >> 1, j2 = j >> 1;
    float v;
    if ((i & 1) == 0) {
        if ((j & 1) == 0) {
            v = in[i2 * rp + j2];
        } else {
            float a = in[i2 * rp + j2], b = in[i2 * rp + j2 + 1];
            v = a * 0.5f + b * 0.5f;
        }
    } else {
        if ((j & 1) == 0) {
            float a = in[i2 * rp + j2], b = in[(i2 + 1) * rp + j2];
            v = a * 0.5f + b * 0.5f;
        } else {
            float a = in[i2 * rp + j2],      c = in[i2 * rp + j2 + 1];
            float b = in[(i2 + 1) * rp + j2], d = in[(i2 + 1) * rp + j2 + 1];
            float t1 = a * 0.5f + b * 0.5f;
            float t2 = c * 0.5f + d * 0.5f;
            v = t1 * 0.5f + t2 * 0.5f;
        }
    }
    return v;
}

__device__ __forceinline__ uint32_t mkkey(float v) {
    float unc = -fabsf(v - 0.5f);
    uint32_t u = __float_as_uint(unc);
    return (u & 0x80000000u) ? ~u : (u | 0x80000000u);
}

__device__ __forceinline__ uint32_t key_of(const float* __restrict__ in, int rp, int r, int n) {
    return mkkey(up2x(in, rp, r, n));
}

// ---------------- bounded all-arrived wait on a counter (64-block scale only) ----------------
__device__ bool wait_ctr(uint32_t* ctr, uint32_t target, volatile uint32_t* sflag) {
    if (threadIdx.x == 0) {
        uint32_t d = aload(ctr);
        int sp = 0;
        while (d < target && sp < 20000) {
            __builtin_amdgcn_s_sleep(4);
            d = aload(ctr);
            ++sp;
        }
        *sflag = (d >= target) ? 1u : 0u;
    }
    __syncthreads();
    return *sflag != 0;
}

// ---------------- eval0 + zero all per-stage buffers ----------------
__global__ __launch_bounds__(256) void k_eval0z(const float* __restrict__ w1, const float* __restrict__ b1,
                                                const float* __restrict__ w2, const float* __restrict__ b2,
                                                float* __restrict__ occ, uint32_t* __restrict__ zbuf, int zcount) {
    __shared__ alignas(16) float sw1[2 * HID];
    __shared__ alignas(16) float sb1[HID];
    __shared__ alignas(16) float sw2[HID];
    int tid = threadIdx.x;
    for (int i = tid; i < 2 * HID; i += 256) sw1[i] = w1[i];
    sb1[tid] = b1[tid];
    sw2[tid] = w2[tid];
    __syncthreads();
    int gtid = blockIdx.x * 256 + tid;
    int nthreads = gridDim.x * 256;
    for (int i = gtid; i < zcount; i += nthreads) zbuf[i] = 0;
    for (int n = gtid; n < 65 * 65; n += nthreads) {
        int i = n / 65, j = n % 65;
        occ[n] = mlp_eval4(16.0f * (float)j, 16.0f * (float)i,
                           (const float4*)sw1, (const float4*)(sw1 + HID),
                           (const float4*)sb1, (const float4*)sw2, b2[0]);
    }
}

// ================= stage 1 fully fused: 64 blocks, 4 counter events (round-7 validated) ======
__global__ __launch_bounds__(256) void k_s1all(const float* __restrict__ in,
                                               float* __restrict__ outg,
                                               uint32_t* __restrict__ keys,
                                               uint32_t* __restrict__ sm,
                                               const float* __restrict__ w1, const float* __restrict__ b1,
                                               const float* __restrict__ w2, const float* __restrict__ b2) {
    __shared__ alignas(16) float sw1[2 * HID];
    __shared__ alignas(16) float sb1[HID];
    __shared__ alignas(16) float sw2[HID];
    __shared__ alignas(16) uint32_t lh[2048];
    __shared__ uint32_t selidx[SELMAX];
    __shared__ uint32_t selcnt;
    __shared__ uint32_t lds4[4];
    __shared__ uint32_t ldspair[2];
    __shared__ uint32_t sflag;

    uint32_t* histA = sm + HISTA_OFF;
    uint32_t* histB = sm + HISTB_OFF;
    uint32_t* histC = sm + HISTC_OFF;
    uint32_t* scal  = sm + SCAL_OFF;
    uint32_t* tic   = sm + TIC_OFF;

    const int tid = threadIdx.x, lane = tid & 63, w = tid >> 6;
    for (int i = tid; i < 2 * HID; i += 256) sw1[i] = w1[i];
    sb1[tid] = b1[tid];
    sw2[tid] = w2[tid];
    if (tid == 0) selcnt = 0;
    for (int k = tid; k < 2048; k += 256) lh[k] = 0;
    __syncthreads();

    // ---- phase A: upsample + keys (atomic stores) + level-1 hist ----
    for (int n0 = blockIdx.x * 256; n0 < N1; n0 += B1 * 256) {
        int n = n0 + tid;
        bool act = n < N1;
        uint32_t key = 0;
        if (act) {
            float v = up2x(in, R1P, R1, n);
            outg[n] = v;                 // plain: consumed only by NEXT dispatch
            key = mkkey(v);
            astore(&keys[n], key);       // atomic: consumed within THIS kernel cross-block
        }
        hist_add(lh, key >> 21, act, lane);
    }
    __syncthreads();
    {
        uint32_t* rep = histA + (size_t)(blockIdx.x & (NREP1 - 1)) * 2048;
        for (int k = tid; k < 2048; k += 256) { uint32_t c = lh[k]; if (c) atomicAdd(&rep[k], c); }
    }
    __syncthreads();   // drains this block's vm ops before arrival publish
    if (tid == 0) __hip_atomic_fetch_add(&scal[8], 1u, __ATOMIC_RELAXED, __HIP_MEMORY_SCOPE_AGENT);

    uint32_t pfx1, rem1;
    if (wait_ctr(&scal[8], B1, &sflag)) {
        scan_atomic(histA, 2048, NREP1, NPT1, 0u, 0, &pfx1, &rem1, lds4, ldspair);
    } else {
        for (int k = tid; k < 2048; k += 256) lh[k] = 0;
        __syncthreads();
        for (int n0 = 0; n0 < N1; n0 += 256) {
            int n = n0 + tid; bool act = n < N1;
            uint32_t key = act ? key_of(in, R1P, R1, n) : 0u;
            hist_add(lh, key >> 21, act, lane);
        }
        __syncthreads();
        scan_generic(lh, 2048, 1, NPT1, 0u, 0, &pfx1, &rem1, lds4, ldspair);
    }

    // ---- phase B: level-2 hist ----
    for (int k = tid; k < 2048; k += 256) lh[k] = 0;
    __syncthreads();
    for (int n0 = blockIdx.x * 256; n0 < N1; n0 += B1 * 256) {
        int n = n0 + tid;
        bool act = n < N1;
        uint32_t key = act ? aload(&keys[n]) : 0u;
        bool flt = act && ((key >> 21) == pfx1);
        hist_add(lh, (key >> 10) & 0x7FFu, flt, lane);
    }
    __syncthreads();
    {
        uint32_t* rep = histB + (size_t)(blockIdx.x & (NREP1 - 1)) * 2048;
        for (int k = tid; k < 2048; k += 256) { uint32_t c = lh[k]; if (c) atomicAdd(&rep[k], c); }
    }
    __syncthreads();
    if (tid == 0) __hip_atomic_fetch_add(&scal[9], 1u, __ATOMIC_RELAXED, __HIP_MEMORY_SCOPE_AGENT);

    uint32_t pfx2, rem2;
    if (wait_ctr(&scal[9], B1, &sflag)) {
        scan_atomic(histB, 2048, NREP1, rem1, pfx1, 11, &pfx2, &rem2, lds4, ldspair);
    } else {
        for (int k = tid; k < 2048; k += 256) lh[k] = 0;
        __syncthreads();
        for (int n0 = 0; n0 < N1; n0 += 256) {
            int n = n0 + tid; bool act = n < N1;
            uint32_t key = act ? key_of(in, R1P, R1, n) : 0u;
            bool flt = act && ((key >> 21) == pfx1);
            hist_add(lh, (key >> 10) & 0x7FFu, flt, lane);
        }
        __syncthreads();
        scan_generic(lh, 2048, 1, rem1, pfx1, 11, &pfx2, &rem2, lds4, ldspair);
    }

    // ---- phase C: level-3 hist (1024 bins) ----
    for (int k = tid; k < 2048; k += 256) lh[k] = 0;
    __syncthreads();
    for (int n0 = blockIdx.x * 256; n0 < N1; n0 += B1 * 256) {
        int n = n0 + tid;
        bool act = n < N1;
        uint32_t key = act ? aload(&keys[n]) : 0u;
        bool flt = act && ((key >> 10) == pfx2);
        hist_add(lh, key & 0x3FFu, flt, lane);
    }
    __syncthreads();
    {
        uint32_t* rep = histC + (size_t)(blockIdx.x & (NREP1 - 1)) * 1024;
        for (int k = tid; k < 1024; k += 256) { uint32_t c = lh[k]; if (c) atomicAdd(&rep[k], c); }
    }
    __syncthreads();
    if (tid == 0) __hip_atomic_fetch_add(&scal[10], 1u, __ATOMIC_RELAXED, __HIP_MEMORY_SCOPE_AGENT);

    uint32_t K, t;
    if (wait_ctr(&scal[10], B1, &sflag)) {
        scan_atomic(histC, 1024, NREP1, rem2, pfx2, 10, &K, &t, lds4, ldspair);
    } else {
        for (int k = tid; k < 2048; k += 256) lh[k] = 0;
        __syncthreads();
        for (int n0 = 0; n0 < N1; n0 += 256) {
            int n = n0 + tid; bool act = n < N1;
            uint32_t key = act ? key_of(in, R1P, R1, n) : 0u;
            bool flt = act && ((key >> 10) == pfx2);
            hist_add(lh, key & 0x3FFu, flt, lane);
        }
        __syncthreads();
        scan_generic(lh, 1024, 1, rem2, pfx2, 10, &K, &t, lds4, ldspair);
    }

    // ---- phase D: per-wave tie counts, publish, wait, prefix ----
    int wv = blockIdx.x * 4 + w;
    int s0 = wv * SEG1;
    int s1e = s0 + SEG1; if (s1e > N1) s1e = N1;
    uint32_t tcnt = 0;
    for (int base = s0; base < s1e; base += 64) {
        int n = base + lane;
        if (n < s1e) tcnt += (aload(&keys[n]) == K) ? 1u : 0u;
    }
#pragma unroll
    for (int d = 32; d; d >>= 1) tcnt += (uint32_t)__shfl_down((int)tcnt, d, 64);
    if (lane == 0) astore(&tic[wv], tcnt);
    __syncthreads();
    if (tid == 0) __hip_atomic_fetch_add(&scal[11], 1u, __ATOMIC_RELAXED, __HIP_MEMORY_SCOPE_AGENT);

    uint32_t tp = 0;
    if (wait_ctr(&scal[11], B1, &sflag)) {
        for (int i = lane; i < wv; i += 64) tp += aload(&tic[i]);
    } else {
        for (int i = lane; i < wv; i += 64) {
            int a0 = i * SEG1, a1 = a0 + SEG1; if (a1 > N1) a1 = N1;
            uint32_t c = 0;
            for (int n2 = a0; n2 < a1; ++n2) c += (key_of(in, R1P, R1, n2) == K) ? 1u : 0u;
            tp += c;
        }
    }
#pragma unroll
    for (int d = 32; d; d >>= 1) tp += (uint32_t)__shfl_down((int)tp, d, 64);
    tp = (uint32_t)__shfl((int)tp, 0, 64);

    // ---- phase E: selection into LDS ----
    uint32_t tie_run = tp;
    unsigned long long lowmask = (lane == 63) ? ~0ull >> 1 : ((1ull << lane) - 1ull);
    for (int base = s0; base < s1e; base += 64) {
        int n = base + lane;
        bool inb = n < s1e;
        uint32_t key = inb ? aload(&keys[n]) : 0u;
        bool gt = inb && (key > K);
        bool tie = inb && (key == K);
        unsigned long long tm = __ballot(tie);
        uint32_t trank = tie_run + (uint32_t)__popcll(tm & lowmask);
        bool sel = gt || (tie && trank < t);
        unsigned long long smk = __ballot(sel);
        if (smk) {
            int leader = __ffsll(smk) - 1;
            uint32_t wbase = 0;
            if (lane == leader) wbase = atomicAdd(&selcnt, (uint32_t)__popcll(smk));
            wbase = (uint32_t)__shfl((int)wbase, leader, 64);
            if (sel) selidx[wbase + (uint32_t)__popcll(smk & lowmask)] = (uint32_t)n;
        }
        tie_run += (uint32_t)__popcll(tm);
    }
    __syncthreads();

    // ---- phase F: eval own selected points (<=264 per block at s1) ----
    uint32_t cnt = selcnt;
    float vb2 = b2[0];
    for (uint32_t i = tid; i < cnt; i += 256) {
        int n = (int)selidx[i];
        int ii = n / R1, jj = n % R1;
        float rr = mlp_eval4(8.0f * (float)jj, 8.0f * (float)ii,
                             (const float4*)sw1, (const float4*)(sw1 + HID),
                             (const float4*)sb1, (const float4*)sw2, vb2);
        outg[n] = rr;
    }
}

// ---------------- upsample 2x + key + msb-11 hist (grid-stride; LDS hist only) ----------------
__global__ __launch_bounds__(256) void k_upkey(const float* __restrict__ in, int rp,
                                               float* __restrict__ outg, int r, int nb, int bstride,
                                               uint32_t* __restrict__ keys,
                                               uint32_t* __restrict__ histA) {
    __shared__ uint32_t hist[2048];
    int tid = threadIdx.x;
    for (int k = tid; k < 2048; k += 256) hist[k] = 0;
    __syncthreads();
    int N = r * r;
    int lane = tid & 63;
    int gstride = gridDim.x * 256;
    for (int n0 = blockIdx.x * 256; n0 < N; n0 += gstride) {
        int n = n0 + tid;
        bool act = n < N;
        uint32_t key = 0;
        if (act) {
            float v = up2x(in, rp, r, n);
            for (int k = 0; k < nb; ++k) outg[(size_t)k * bstride + n] = v;
            key = mkkey(v);
            keys[n] = key;
        }
        hist_add(hist, key >> 21, act, lane);
    }
    __syncthreads();
    uint32_t* myrep = histA + (size_t)(blockIdx.x & (NREP - 1)) * 2048;
    for (int k = tid; k < 2048; k += 256) {
        uint32_t c = hist[k];
        if (c) atomicAdd(&myrep[k], c);
    }
}

// ---------------- filtered histogram pass (scan of prev hist fused in, per block) ----------------
__global__ __launch_bounds__(256) void k_histmid(const uint32_t* __restrict__ keys, int N,
                                                 const uint32_t* __restrict__ prevHist,
                                                 uint32_t* __restrict__ scal,
                                                 int useNpt, uint32_t npt, int scalInIdx, int shift,
                                                 int scalOutIdx,
                                                 int fshift, int bshift, uint32_t bmask,
                                                 uint32_t* __restrict__ outHist, int NBout) {
    __shared__ uint32_t lh[2048];
    __shared__ uint32_t lds4[4];
    __shared__ uint32_t ldspair[2];
    int tid = threadIdx.x, lane = tid & 63;
    uint32_t rem_in = useNpt ? npt : scal[scalInIdx + 1];
    uint32_t pfx_in = useNpt ? 0u  : scal[scalInIdx];
    uint32_t pfx, rem;
    scan_generic(prevHist, 2048, NREP, rem_in, pfx_in, shift, &pfx, &rem, lds4, ldspair);
    if (blockIdx.x == 0 && tid == 0) { scal[scalOutIdx] = pfx; scal[scalOutIdx + 1] = rem; }
    for (int k = tid; k < 2048; k += 256) lh[k] = 0;
    __syncthreads();
    int gstride = gridDim.x * 256;
    for (int base = blockIdx.x * 256; base < N; base += gstride) {
        int n = base + tid;
        bool inb = n < N;
        uint32_t key = inb ? keys[n] : 0u;
        bool flt = inb && ((key >> fshift) == pfx);
        uint32_t bin = (key >> bshift) & bmask;
        hist_add(lh, bin, flt, lane);
    }
    __syncthreads();
    uint32_t* myrep = outHist + (size_t)(blockIdx.x & (NREP - 1)) * NBout;
    for (int k = tid; k < NBout; k += 256) {
        uint32_t c = lh[k];
        if (c) atomicAdd(&myrep[k], c);
    }
}

// ---------------- fused final-scan + ORDERED selection via (tie,gt) pair lookback -------------
// Flag64 layout: [63:62]=status (1=aggregate, 2=inclusive), [47:24]=tie count, [23:0]=gt count.
// Forward-only lookback (validated cheap pattern); bounded spin with recompute-from-keys
// fallback -> G16-safe, cannot hang. Exclusive (tie,gt) prefixes give each selected point a
// closed-form global slot: selbuf ends up SORTED BY INDEX -> coalesced compaction writes and
// coalesced evalsel reads/writes (kills the round-7 scatter penalty).
__global__ __launch_bounds__(256, 2) void k_segselc(
        const uint32_t* __restrict__ keys, int N, int seglen,
        const uint32_t* __restrict__ histC,
        const uint32_t* __restrict__ scal,
        unsigned long long* __restrict__ tic64,
        uint32_t* __restrict__ selbuf) {
    __shared__ uint32_t lds4[4];
    __shared__ uint32_t ldspair[2];
    __shared__ uint32_t wtc[4], wgc[4];
    __shared__ uint32_t s_excl_t, s_excl_g;
    int tid = threadIdx.x, lane = tid & 63, w = tid >> 6;
    if (tid == 0) { s_excl_t = 0; s_excl_g = 0; }

    // K,t via redundant per-block scan of histC (built by previous dispatch)
    uint32_t rem2 = scal[3], pfx2 = scal[2];
    uint32_t K, t;
    scan_generic(histC, 1024, NREP, rem2, pfx2, 10, &K, &t, lds4, ldspair);

    // ---- pass 1: per-wave tie AND gt counts over own segment ----
    int wv = blockIdx.x * 4 + w;
    int s0 = wv * seglen;
    int s1 = s0 + seglen; if (s1 > N) s1 = N;
    uint32_t tcnt = 0, gcnt2 = 0;
    for (int base = s0; base < s1; base += 64) {
        int n = base + lane;
        if (n < s1) {
            uint32_t key = keys[n];
            tcnt += (key == K) ? 1u : 0u;
            gcnt2 += (key > K) ? 1u : 0u;
        }
    }
#pragma unroll
    for (int d = 32; d; d >>= 1) {
        tcnt += (uint32_t)__shfl_down((int)tcnt, d, 64);
        gcnt2 += (uint32_t)__shfl_down((int)gcnt2, d, 64);
    }
    if (lane == 0) { wtc[w] = tcnt; wgc[w] = gcnt2; }
    __syncthreads();
    uint32_t agg_t = wtc[0] + wtc[1] + wtc[2] + wtc[3];
    uint32_t agg_g = wgc[0] + wgc[1] + wgc[2] + wgc[3];
    uint32_t intra_t = 0, intra_g = 0;
    for (int i = 0; i < w; ++i) { intra_t += wtc[i]; intra_g += wgc[i]; }

    // ---- publish aggregate; block 0 publishes inclusive directly ----
    if (tid == 0) {
        unsigned long long pay = ((unsigned long long)agg_t << 24) | (unsigned long long)agg_g;
        unsigned long long st = (blockIdx.x == 0) ? ((2ull << 62) | pay) : ((1ull << 62) | pay);
        astore64(&tic64[blockIdx.x], st);
    }
    // ---- bounded decoupled pair-lookback (wave 0, 64 predecessors per round) ----
    if (blockIdx.x > 0 && w == 0) {
        uint32_t excl_t = 0, excl_g = 0;
        int b = (int)blockIdx.x - 1;
        for (;;) {
            int mine = b - lane;
            bool active = (mine >= 0);
            unsigned long long f = 0;
            if (active) {
                f = aload64(&tic64[mine]);
                int spins = 0;
                while ((f >> 62) == 0ull && spins < 1000) {
                    __builtin_amdgcn_s_sleep(2);
                    f = aload64(&tic64[mine]);
                    ++spins;
                }
                if ((f >> 62) == 0ull) {
                    // fallback: count that segment-group's tie/gt directly (bounded, no hang)
                    int ms0 = mine * 4 * seglen;
                    int ms1 = ms0 + 4 * seglen; if (ms1 > N) ms1 = N;
                    uint32_t ct = 0, cg = 0;
                    for (int n2 = ms0; n2 < ms1; ++n2) {
                        uint32_t key = keys[n2];
                        ct += (key == K) ? 1u : 0u;
                        cg += (key > K) ? 1u : 0u;
                    }
                    f = (1ull << 62) | ((unsigned long long)ct << 24) | (unsigned long long)cg;
                }
            }
            unsigned long long incm = __ballot(active && (f >> 62) == 2ull);
            uint32_t vt, vg;
            bool done = (incm != 0ull);
            if (done) {
                int l2 = __ffsll(incm) - 1;   // nearest predecessor with inclusive prefix
                vt = (lane <= l2) ? (uint32_t)((f >> 24) & 0xFFFFFFull) : 0u;
                vg = (lane <= l2) ? (uint32_t)(f & 0xFFFFFFull) : 0u;
            } else {
                vt = active ? (uint32_t)((f >> 24) & 0xFFFFFFull) : 0u;
                vg = active ? (uint32_t)(f & 0xFFFFFFull) : 0u;
            }
#pragma unroll
            for (int d = 32; d; d >>= 1) {
                vt += (uint32_t)__shfl_down((int)vt, d, 64);
                vg += (uint32_t)__shfl_down((int)vg, d, 64);
            }
            vt = (uint32_t)__shfl((int)vt, 0, 64);
            vg = (uint32_t)__shfl((int)vg, 0, 64);
            excl_t += vt;
            excl_g += vg;
            if (done) break;
            if (b < 64) break;    // all remaining predecessors summed directly
            b -= 64;
        }
        if (lane == 0) {
            unsigned long long pay = ((unsigned long long)(excl_t + agg_t) << 24)
                                   | (unsigned long long)(excl_g + agg_g);
            astore64(&tic64[blockIdx.x], (2ull << 62) | pay);
            s_excl_t = excl_t;
            s_excl_g = excl_g;
        }
    }
    __syncthreads();
    uint32_t tie_run = s_excl_t + intra_t;
    uint32_t gt_run  = s_excl_g + intra_g;

    // ---- pass 2: ordered selection, write selbuf[dest] directly (keys L1-hot) ----
    // dest(gt at n)  = gt_prefix(n) + min(t, tie_prefix(n))
    // dest(tie at n) = gt_prefix(n) + tie_rank          (selected iff tie_rank < t)
    unsigned long long lowmask = (lane == 63) ? ~0ull >> 1 : ((1ull << lane) - 1ull);
    for (int base = s0; base < s1; base += 64) {
        int n = base + lane;
        bool inb = n < s1;
        uint32_t key = inb ? keys[n] : 0u;
        bool gt = inb && (key > K);
        bool tie = inb && (key == K);
        unsigned long long tm = __ballot(tie);
        unsigned long long gm = __ballot(gt);
        uint32_t tie_before = tie_run + (uint32_t)__popcll(tm & lowmask);
        uint32_t gt_before  = gt_run + (uint32_t)__popcll(gm & lowmask);
        if (gt) {
            uint32_t tb = tie_before < t ? tie_before : t;
            selbuf[gt_before + tb] = (uint32_t)n;
        } else if (tie && tie_before < t) {
            selbuf[gt_before + tie_before] = (uint32_t)n;
        }
        tie_run += (uint32_t)__popcll(tm);
        gt_run  += (uint32_t)__popcll(gm);
    }
}

// ---------------- balanced eval of ordered compacted selection (2 pts/thread, shared reads) ---
__global__ __launch_bounds__(256) void k_evalsel(const uint32_t* __restrict__ selbuf, int npt,
                                                 int r, float stride,
                                                 float* __restrict__ occ, int nb, int bstride,
                                                 const float* __restrict__ w1, const float* __restrict__ b1,
                                                 const float* __restrict__ w2, const float* __restrict__ b2) {
    __shared__ alignas(16) float sw1[2 * HID];
    __shared__ alignas(16) float sb1[HID];
    __shared__ alignas(16) float sw2[HID];
    int tid = threadIdx.x;
    for (int i = tid; i < 2 * HID; i += 256) sw1[i] = w1[i];
    sb1[tid] = b1[tid];
    sw2[tid] = w2[tid];
    __syncthreads();
    float vb2 = b2[0];
    const float4* w1x = (const float4*)sw1;
    const float4* w1y = (const float4*)(sw1 + HID);
    const float4* vb1 = (const float4*)sb1;
    const float4* vw2 = (const float4*)sw2;
    const float C0 = (float)(0.5 / 1025.0);
    int gs2 = gridDim.x * 512;
    for (int bb = blockIdx.x * 512; bb < npt; bb += gs2) {
        int i0 = bb + tid, i1 = bb + tid + 256;
        bool v0 = i0 < npt, v1 = i1 < npt;
        int nA = v0 ? (int)selbuf[i0] : 0;
        int nB = v1 ? (int)selbuf[i1] : 0;
        int iA = nA / r, jA = nA % r;
        int iB = nB / r, jB = nB % r;
        float pxA = ((stride * (float)jA) / 1025.0f + C0) * 2.0f - 1.0f;
        float pyA = ((stride * (float)iA) / 1025.0f + C0) * 2.0f - 1.0f;
        float pxB = ((stride * (float)jB) / 1025.0f + C0) * 2.0f - 1.0f;
        float pyB = ((stride * (float)iB) / 1025.0f + C0) * 2.0f - 1.0f;
        float4 A0 = {0, 0, 0, 0}, A1 = {0, 0, 0, 0};
#pragma unroll 4
        for (int q = 0; q < HID / 4; ++q) {
            float4 a = w1x[q], b = w1y[q], c = vb1[q], d = vw2[q];
            {
                float h0 = pxA * a.x + pyA * b.x + c.x;
                float h1 = pxA * a.y + pyA * b.y + c.y;
                float h2 = pxA * a.z + pyA * b.z + c.z;
                float h3 = pxA * a.w + pyA * b.w + c.w;
                h0 = h0 > 0.f ? h0 : 0.f;
                h1 = h1 > 0.f ? h1 : 0.f;
                h2 = h2 > 0.f ? h2 : 0.f;
                h3 = h3 > 0.f ? h3 : 0.f;
                A0.x += h0 * d.x; A0.y += h1 * d.y;
                A0.z += h2 * d.z; A0.w += h3 * d.w;
            }
            {
                float h0 = pxB * a.x + pyB * b.x + c.x;
                float h1 = pxB * a.y + pyB * b.y + c.y;
                float h2 = pxB * a.z + pyB * b.z + c.z;
                float h3 = pxB * a.w + pyB * b.w + c.w;
                h0 = h0 > 0.f ? h0 : 0.f;
                h1 = h1 > 0.f ? h1 : 0.f;
                h2 = h2 > 0.f ? h2 : 0.f;
                h3 = h3 > 0.f ? h3 : 0.f;
                A1.x += h0 * d.x; A1.y += h1 * d.y;
                A1.z += h2 * d.z; A1.w += h3 * d.w;
            }
        }
        if (v0) {
            float x = ((A0.x + A0.y) + (A0.z + A0.w)) + vb2;
            float rr;
            if (x >= 0.f) { rr = 1.0f / (1.0f + expf(-x)); }
            else { float e = expf(x); rr = e / (1.0f + e); }
            for (int k = 0; k < nb; ++k) occ[(size_t)k * bstride + nA] = rr;
        }
        if (v1) {
            float x = ((A1.x + A1.y) + (A1.z + A1.w)) + vb2;
            float rr;
            if (x >= 0.f) { rr = 1.0f / (1.0f + expf(-x)); }
            else { float e = expf(x); rr = e / (1.0f + e); }
            for (int k = 0; k < nb; ++k) occ[(size_t)k * bstride + nB] = rr;
        }
    }
}

// ---------------- fallback-only broadcast (used when d_ws is too small) ----------------
__global__ __launch_bounds__(256) void k_bcast(const float* __restrict__ src, float* __restrict__ dst, int N) {
    int q = blockIdx.x * 256 + threadIdx.x;
    int n = q * 4;
    if (n + 3 < N) {
        float4 v = *(const float4*)(src + n);
#pragma unroll
        for (int k = 0; k < 8; ++k) *(float4*)(dst + (size_t)k * N + n) = v;
    } else if (n < N) {
        for (int m = n; m < N; ++m) {
            float v = src[m];
#pragma unroll
            for (int k = 0; k < 8; ++k) dst[(size_t)k * N + m] = v;
        }
    }
}

extern "C" void kernel_launch(void* const* d_in, const int* in_sizes, int n_in,
                              void* d_out, int out_size, void* d_ws, size_t ws_size,
                              hipStream_t stream) {
    const float* w1 = (const float*)d_in[0];
    const float* b1 = (const float*)d_in[1];
    const float* w2 = (const float*)d_in[2];
    const float* b2 = (const float*)d_in[3];
    float* out = (float*)d_out;

    const size_t A = (((size_t)NMAXPIX * 4) + 255) & ~(size_t)255;  // one grid buffer
    const size_t SMALL_BYTES = (size_t)4 * STAGE_U32 * 4;            // 4 stage regions
    const size_t SELB_BYTES = ((size_t)262144 * 4 + 255) & ~(size_t)255;
    const size_t need = 3 * A + SMALL_BYTES + SELB_BYTES;

    int fused8 = (ws_size >= need);  // stage-4 writes all 8 batches directly only when ws holds scratch
    char* base = fused8 ? (char*)d_ws : (char*)d_out;
    float* buf0 = (float*)(base);
    float* buf1 = (float*)(base + A);
    uint32_t* keys = (uint32_t*)(base + 2 * A);
    uint32_t* smallb = (uint32_t*)(base + 3 * A);
    uint32_t* selbuf = (uint32_t*)(base + 3 * A + SMALL_BYTES);

    // dispatch 1: zero all stage buffers (hists, scal incl. counters, tic) + dense 65x65 eval
    k_eval0z<<<dim3(512), dim3(256), 0, stream>>>(w1, b1, w2, b2, buf0, smallb, 4 * STAGE_U32);

    // ---- stage 1 (129x129): ONE fused kernel, 64 blocks, counter events ----
    k_s1all<<<dim3(B1), dim3(256), 0, stream>>>(buf0, buf1, keys, smallb, w1, b1, w2, b2);

    const int resA[5] = {65, 129, 257, 513, 1025};
    const int nptA[5] = {0, 4096, 16384, 65536, 262144};
    float* cur = buf1;
    float* nxt = buf0;
    for (int s = 2; s < 5; ++s) {
        int rp = resA[s - 1], r = resA[s];
        int N = r * r;
        uint32_t npt = (uint32_t)nptA[s];
        uint32_t* sm    = smallb + (size_t)(s - 1) * STAGE_U32;
        uint32_t* histA = sm + HISTA_OFF;
        uint32_t* histB = sm + HISTB_OFF;
        uint32_t* histC = sm + HISTC_OFF;
        uint32_t* scal  = sm + SCAL_OFF;
        uint32_t* tic   = sm + TIC_OFF;
        int nb1 = (N + 255) / 256;
        int nbu = nb1 < 1024 ? nb1 : 1024;
        int seglen = (N + NSEG - 1) / NSEG;
        float stride = 1024.0f / (float)(r - 1);

        int last = (s == 4);
        float* stage_out = (last && fused8) ? out : nxt;
        int nb = (last && fused8) ? 8 : 1;
        int bstride = (last && fused8) ? NMAXPIX : 0;

        int nbe = (int)((npt + 511) / 512); if (nbe > 512) nbe = 512;

        k_upkey<<<dim3(nbu), dim3(256), 0, stream>>>(cur, rp, stage_out, r, nb, bstride, keys, histA);
        k_histmid<<<dim3(512), dim3(256), 0, stream>>>(keys, N, histA, scal, 1, npt, 0, 0,
                                                       0, 21, 10, 0x7FFu, histB, 2048);
        k_histmid<<<dim3(512), dim3(256), 0, stream>>>(keys, N, histB, scal, 0, 0u, 0, 11,
                                                       2, 10, 0, 0x3FFu, histC, 1024);
        k_segselc<<<dim3(NSEG / 4), dim3(256), 0, stream>>>(keys, N, seglen, histC, scal,
                                                            (unsigned long long*)tic, selbuf);
        k_evalsel<<<dim3(nbe), dim3(256), 0, stream>>>(selbuf, (int)npt, r, stride,
                                                       stage_out, nb, bstride, w1, b1, w2, b2);
        if (!(last && fused8)) { float* tmp = cur; cur = nxt; nxt = tmp; }
    }
    if (!fused8) {
        // fallback: scratch lived in d_out; final grid is at cur
        k_bcast<<<dim3(((NMAXPIX + 3) / 4 + 255) / 256), dim3(256), 0, stream>>>(cur, out, NMAXPIX);
    }
}